// Round 12
// baseline (469.262 us; speedup 1.0000x reference)
//
#include <hip/hip_runtime.h>
#include <hip/hip_bf16.h>

typedef unsigned short u16;
typedef unsigned int   u32;
typedef _Float16 h2 __attribute__((ext_vector_type(2)));
typedef short s8v __attribute__((ext_vector_type(8)));
typedef float f4v __attribute__((ext_vector_type(4)));
typedef u16 u16x4 __attribute__((ext_vector_type(4)));

#define N_NODES 50000
#define N_EDGES 800000

// binned bucket construction
#define RPB   250        // receivers per bin
#define NBINS 200
#define EPB   4096       // edges per block in binning kernels
#define NBB   ((N_EDGES+EPB-1)/EPB)   // 196

// fused pass geometry
#define EPS   64         // edges per sweep (4 tiles x 16)

// ---- ws layout (u32 units) ----
#define WB_W1H  0        // [64][4] u32 half2 (fp16 pairs of W1 columns)
#define WB_B1   256      // [64] f32
#define WB_W2F  320      // 5120 bf16 = 2560 u32, MFMA B-frag layout
#define WB_WINS 2880
#define WB_WINV 3136
#define WB_WOS  3392
#define WB_WOV  4416
#define WB_SCS  5184
#define WB_SCV  7232
#define WB_FLAG 8256
#define OFF_SV16 8260    // [50000][16][4] u16 (xs,x0,x1,x2)
#define IDX_BCNT 1608260 // 200 ints
#define IDX_BOF2 1608516 // 200 ints
#define IDX_BCUR 1608772 // 200 ints
#define IDX_OFFS 1658260 // 50001 ints
#define IDX_BUCK 1758262 // 800,000 int
#define IDX_EEID 2558264 // 800,000 u32 (bin-grouped edge ids)
#define OFF_ER16 3358264 // 800,000 u16 (bin-grouped receivers)
#define OFF_REC  3758264 // [N_EDGES] packed edge record, <=16 u32 stride (64B-aligned)
#define ACC_OFF  16558264 // 50,000 x 176 f32 accumulators

__device__ __forceinline__ float bf2f(u16 v){
  union { u32 u; float f; } x; x.u = ((u32)v) << 16; return x.f;
}
__device__ __forceinline__ u16 f2bf(float f){
  u32 u = __float_as_uint(f);
  u32 lsb = (u >> 16) & 1u;
  u32 r = u + 0x7fffu + lsb;
  return (u16)(r >> 16);
}
__device__ __forceinline__ float ldx(const void* p, long long i, int isf){
  return isf ? ((const float*)p)[i] : bf2f(((const u16*)p)[i]);
}
__device__ __forceinline__ u32 pkh2(float a, float b){
  union { u32 u; h2 v; } x; x.v.x = (_Float16)a; x.v.y = (_Float16)b; return x.u;
}
__device__ __forceinline__ float dot2(h2 a, u32 w, float c){
  union { u32 u; h2 v; } x; x.u = w;
#if __has_builtin(__builtin_amdgcn_fdot2)
  return __builtin_amdgcn_fdot2(a, x.v, c, false);
#else
  return c + (float)a.x*(float)x.v.x + (float)a.y*(float)x.v.y;
#endif
}
__device__ __forceinline__ float sigmoidf_(float x){ return 1.f/(1.f + __expf(-x)); }

__global__ void detect_dtype(const u32* __restrict__ remb_raw, int* __restrict__ flag){
  int t = threadIdx.x;           // 64 lanes, one word each
  u32 w = remb_raw[t];
  u32 lo = w & 0xffffu, hi = w >> 16;
  int okl = ((lo & 0x8000u) == 0) && (((lo >> 7) & 0xffu) <= 126u);
  int okh = ((hi & 0x8000u) == 0) && (((hi >> 7) & 0xffu) <= 126u);
  unsigned long long bad = __ballot(!(okl && okh));
  if (t == 0) *flag = (bad != 0ull) ? 1 : 0;
}

__global__ void prep_weights(const void* __restrict__ w1, const void* __restrict__ b1g,
                             const void* __restrict__ w2, const void* __restrict__ wins,
                             const void* __restrict__ winv, const void* __restrict__ wos,
                             const void* __restrict__ wov, const void* __restrict__ scs,
                             const void* __restrict__ scv, float* __restrict__ wbuf,
                             const int* __restrict__ flag){
  int t = threadIdx.x;
  int isf = *flag;
  u32* w1h  = (u32*)(wbuf + WB_W1H);
  u16* w2f  = (u16*)(wbuf + WB_W2F);
  for (int idx=t; idx<256;  idx+=256){
    int j = idx>>2, ip = idx&3;
    w1h[idx] = pkh2(ldx(w1, (2*ip)*64+j, isf), ldx(w1, (2*ip+1)*64+j, isf));
  }
  for (int idx=t; idx<64;   idx+=256){ wbuf[WB_B1+idx]  = ldx(b1g, idx, isf); }
  // MFMA B-frag layout for 16x16x32 bf16: lane holds B[k=(lane>>4)*8+j][n=lane&15]
  for (int idx=t; idx<5120; idx+=256){
    int tt = idx >> 10;           // N-tile 0..4
    int rem = idx & 1023;
    int kh = rem >> 9;            // K-half 0..1
    int rem2 = rem & 511;
    int ln = rem2 >> 3, j = rem2 & 7;
    int k = kh*32 + (ln>>4)*8 + j;
    int o = tt*16 + (ln&15);
    w2f[idx] = f2bf(ldx(w2, (long long)k*80 + o, isf));
  }
  for (int idx=t; idx<256;  idx+=256){ wbuf[WB_WINS+idx] = ldx(wins, idx, isf); }
  for (int idx=t; idx<256;  idx+=256){ wbuf[WB_WINV+idx] = ldx(winv, idx, isf); }
  for (int idx=t; idx<1024; idx+=256){ wbuf[WB_WOS+idx]  = ldx(wos, idx, isf); }
  for (int idx=t; idx<768;  idx+=256){ wbuf[WB_WOV+idx]  = ldx(wov, idx, isf); }
  for (int idx=t; idx<2048; idx+=256){ wbuf[WB_SCS+idx]  = ldx(scs, idx, isf); }
  for (int idx=t; idx<1024; idx+=256){ wbuf[WB_SCV+idx]  = ldx(scv, idx, isf); }
}

// node_pre v2: 256 threads / 16 nodes per block, 16 threads per node.
__global__ void __launch_bounds__(256) node_pre(
    const void* __restrict__ ns_g, const void* __restrict__ nv_g,
    const float* __restrict__ wbuf, u16* __restrict__ sv16,
    const int* __restrict__ flag){
  __shared__ float A[16][16];     // [node][u] scalars
  __shared__ float B[16][48];     // [node][u*3+c] vectors
  __shared__ float wsl[256], wvl[256];
  int tid = threadIdx.x;
  int isf = *flag;
  int n0 = blockIdx.x*16;         // 3125*16 = 50000 exact
  for (int i=tid;i<256;i+=256){ wsl[i]=wbuf[WB_WINS+i]; wvl[i]=wbuf[WB_WINV+i]; }
  for (int i=tid;i<256;i+=256) A[i>>4][i&15] = ldx(ns_g,(long long)n0*16+i,isf);
  for (int i=tid;i<768;i+=256) B[i/48][i%48] = ldx(nv_g,(long long)n0*48+i,isf);
  __syncthreads();
  int g = tid>>4, u = tid&15;
  float s=0.f, v0=0.f, v1=0.f, v2=0.f;
  #pragma unroll
  for (int j=0;j<16;j++){
    s  += A[g][j]*wsl[j*16+u];
    float wv = wvl[j*16+u];
    v0 += B[g][j*3+0]*wv;
    v1 += B[g][j*3+1]*wv;
    v2 += B[g][j*3+2]*wv;
  }
  u16x4 pk;
  pk[0]=f2bf(s); pk[1]=f2bf(v0); pk[2]=f2bf(v1); pk[3]=f2bf(v2);
  ((u16x4*)sv16)[(size_t)(n0+g)*16 + u] = pk;
}

// pack per-edge record in original order (all streamed).
__global__ void __launch_bounds__(256) pack_edges(
    const void* __restrict__ remb, const void* __restrict__ edge_sh,
    const int* __restrict__ senders, u32* __restrict__ rec,
    const int* __restrict__ flag){
  int e = blockIdx.x*256 + threadIdx.x;
  if (e >= N_EDGES) return;
  int isf = *flag;
  if (isf){
    u32* r = rec + (size_t)e*16;
    f4v ra = ((const f4v*)remb)[(size_t)e*2];
    f4v rb = ((const f4v*)remb)[(size_t)e*2+1];
    ((f4v*)r)[0] = ra;
    ((f4v*)r)[1] = rb;
    ((f4v*)r)[2] = ((const f4v*)edge_sh)[e];
    r[12] = (u32)senders[e];
  } else {
    u32* r = rec + (size_t)e*8;
    *(s8v*)r = ((const s8v*)remb)[e];
    const u32* ys = (const u32*)edge_sh + (size_t)e*2;
    r[4]=ys[0]; r[5]=ys[1];
    r[6] = (u32)senders[e];
    r[7] = 0;
  }
}

// ---- binned bucket construction ----
__global__ void __launch_bounds__(256) bin_count(const int* __restrict__ receivers,
                                                 int* __restrict__ bcnt){
  __shared__ int lcnt[NBINS];
  int t = threadIdx.x;
  for (int i=t;i<NBINS;i+=256) lcnt[i]=0;
  __syncthreads();
  int base = blockIdx.x*EPB;
  for (int i=t;i<EPB;i+=256){
    int e = base+i;
    if (e<N_EDGES) atomicAdd(&lcnt[receivers[e]/RPB],1);
  }
  __syncthreads();
  for (int i=t;i<NBINS;i+=256) if (lcnt[i]) atomicAdd(&bcnt[i], lcnt[i]);
}

__global__ void bin_scan(const int* __restrict__ bcnt, int* __restrict__ binoff,
                         int* __restrict__ bincur, int* __restrict__ offs){
  __shared__ int lds[NBINS];
  int t=threadIdx.x;
  if (t<NBINS) lds[t]=bcnt[t];
  __syncthreads();
  for (int off=1; off<NBINS; off<<=1){
    int v = (t<NBINS && t>=off)? lds[t-off] : 0;
    __syncthreads();
    if (t<NBINS) lds[t]+=v;
    __syncthreads();
  }
  if (t<NBINS){ int ex = lds[t]-bcnt[t]; binoff[t]=ex; bincur[t]=ex; }
  if (t==0) offs[N_NODES] = N_EDGES;
}

__global__ void __launch_bounds__(256) bin_scatter(const int* __restrict__ receivers,
                 int* __restrict__ bincur, u32* __restrict__ eeid, u16* __restrict__ er){
  __shared__ int lcnt[NBINS], loff[NBINS], lcur[NBINS], gbase[NBINS];
  __shared__ u32 seid[EPB];
  __shared__ u16 sr[EPB];
  int t = threadIdx.x;
  for (int i=t;i<NBINS;i+=256) lcnt[i]=0;
  __syncthreads();
  int base = blockIdx.x*EPB;
  int r_[16];
  #pragma unroll
  for (int k=0;k<16;k++){
    int e = base + t + k*256;
    r_[k] = (e<N_EDGES)? receivers[e] : -1;
    if (r_[k]>=0) atomicAdd(&lcnt[r_[k]/RPB],1);
  }
  __syncthreads();
  if (t<NBINS) loff[t]=lcnt[t];
  __syncthreads();
  for (int off=1; off<NBINS; off<<=1){
    int v=(t<NBINS&&t>=off)?loff[t-off]:0;
    __syncthreads();
    if (t<NBINS) loff[t]+=v;
    __syncthreads();
  }
  if (t<NBINS){
    int ex=loff[t]-lcnt[t]; loff[t]=ex; lcur[t]=ex;
    gbase[t] = lcnt[t] ? atomicAdd(&bincur[t], lcnt[t]) : 0;
  }
  __syncthreads();
  #pragma unroll
  for (int k=0;k<16;k++){
    if (r_[k]>=0){
      int b=r_[k]/RPB;
      int p=atomicAdd(&lcur[b],1);
      seid[p]=(u32)(base + t + k*256);
      sr[p]=(u16)r_[k];
    }
  }
  __syncthreads();
  int rem = N_EDGES - base;
  int tot = rem < EPB ? rem : EPB;
  for (int i=t;i<tot;i+=256){
    int b = sr[i]/RPB;
    int dst = gbase[b] + (i - loff[b]);
    eeid[dst]=seid[i]; er[dst]=sr[i];
  }
}

__global__ void __launch_bounds__(256) bin_finalize(const u32* __restrict__ eeid,
        const u16* __restrict__ er, const int* __restrict__ binoff,
        const int* __restrict__ bcnt, int* __restrict__ offs, int* __restrict__ bucket){
  __shared__ int deg[RPB], pfx[RPB], lcur[RPB];
  int b=blockIdx.x, t=threadIdx.x;
  int beg=binoff[b], cnt=bcnt[b];
  for (int i=t;i<RPB;i+=256) deg[i]=0;
  __syncthreads();
  int r0=b*RPB;
  for (int i=t;i<cnt;i+=256) atomicAdd(&deg[er[beg+i]-r0],1);
  __syncthreads();
  if (t<RPB) pfx[t]=deg[t];
  __syncthreads();
  for (int off=1; off<RPB; off<<=1){
    int v=(t<RPB&&t>=off)?pfx[t-off]:0;
    __syncthreads();
    if (t<RPB) pfx[t]+=v;
    __syncthreads();
  }
  if (t<RPB){
    int ex=pfx[t]-deg[t]; pfx[t]=ex; lcur[t]=ex;
    offs[r0+t]=beg+ex;
  }
  __syncthreads();
  for (int i=t;i<cnt;i+=256){
    int rr = er[beg+i]-r0;
    int k = atomicAdd(&lcur[rr],1);
    bucket[beg+k] = (int)eeid[beg+i];
  }
}

// pass_fused: block = 2 receivers (4 waves). Per sweep of <=64 ranks:
//   phase A: wave wid MFMAs tile wid (16 edges) -> w/Y/snd into LDS (no global wp)
//   phase B: same 8-chain register reduce as the old pass2, reading LDS.
// Epilogue kept separate (VGPR discipline, round-8 lesson). Grid = N_NODES/2.
__global__ void __launch_bounds__(256, 4) pass_fused(
    const int* __restrict__ bucket, const int* __restrict__ offs,
    const u32* __restrict__ rec, const float* __restrict__ wbuf,
    const u16* __restrict__ sv16, float* __restrict__ accbuf,
    const int* __restrict__ flag){
  __shared__ u16  wp[5][EPS][16];    // w planes, bf16 (same rounding as before)
  __shared__ float yb[EPS][4];
  __shared__ u16  sn[EPS];
  __shared__ u16  hlds[4*16*72];
  __shared__ float part[4][176];
  int tid = threadIdx.x;
  int lane = tid & 63, wid = tid >> 6;
  int u = lane & 15, q = lane >> 4;
  int isf = *flag;
  int r0n = blockIdx.x*2;
  int beg = offs[r0n], end = offs[r0n+2];
  int cnt = end - beg;
  int nsweep = (cnt + EPS - 1) / EPS;
  int pr = wid >> 1, wsub = wid & 1;
  int rbeg = offs[r0n + pr], rend = offs[r0n + pr + 1];

  const u32* w1h = (const u32*)(wbuf + WB_W1H);
  const float* b1 = wbuf + WB_B1;
  const u16* w2f = (const u16*)(wbuf + WB_W2F);
  s8v bfr[5][2];
  #pragma unroll
  for (int t=0;t<5;t++)
    #pragma unroll
    for (int kh=0;kh<2;kh++)
      bfr[t][kh] = *(const s8v*)(w2f + ((t*2+kh)*64 + lane)*8);
  u16* hw = hlds + wid*(16*72);

  float As0=0.f,As1=0.f;
  float Av00=0.f,Av01=0.f,Av02=0.f, Av10=0.f,Av11=0.f,Av12=0.f, Av20=0.f,Av21=0.f,Av22=0.f;

  for (int s=0; s<nsweep; s++){
    int sbeg = beg + s*EPS;
    int tbase = sbeg + wid*16;
    // ---- phase A: wave handles one 16-edge tile ----
    if (tbase < end){
      int e = lane & 15;
      int er = tbase + e;
      int eid = (er < end) ? bucket[er] : 0;
      float re[8];
      if (isf){
        const u32* r = rec + (size_t)eid*16;
        f4v ra = ((const f4v*)r)[0];
        f4v rb = ((const f4v*)r)[1];
        re[0]=ra[0]; re[1]=ra[1]; re[2]=ra[2]; re[3]=ra[3];
        re[4]=rb[0]; re[5]=rb[1]; re[6]=rb[2]; re[7]=rb[3];
        if (q == 0 && er < end){
          int le = er - sbeg;
          *(f4v*)yb[le] = ((const f4v*)r)[2];
          sn[le] = (u16)r[12];
        }
      } else {
        const u32* r = rec + (size_t)eid*8;
        s8v r8 = *(const s8v*)r;
        #pragma unroll
        for (int i=0;i<8;i++) re[i] = bf2f((u16)r8[i]);
        if (q == 0 && er < end){
          int le = er - sbeg;
          u32 y0 = r[4], y1 = r[5];
          f4v y;
          y[0]=bf2f((u16)(y0 & 0xffffu)); y[1]=bf2f((u16)(y0 >> 16));
          y[2]=bf2f((u16)(y1 & 0xffffu)); y[3]=bf2f((u16)(y1 >> 16));
          *(f4v*)yb[le] = y;
          sn[le] = (u16)r[6];
        }
      }
      h2 reh[4];
      #pragma unroll
      for (int ip=0;ip<4;ip++){ reh[ip].x=(_Float16)re[2*ip]; reh[ip].y=(_Float16)re[2*ip+1]; }
      asm volatile("s_waitcnt lgkmcnt(0)" ::: "memory"); // prev sweep's hw reads done
      #pragma unroll
      for (int jj=0;jj<16;jj++){
        int j = q*16 + jj;
        float a = b1[j];
        #pragma unroll
        for (int ip=0;ip<4;ip++) a = dot2(reh[ip], w1h[j*4+ip], a);
        a = a * sigmoidf_(a);
        hw[e*72 + j] = f2bf(a);
      }
      asm volatile("s_waitcnt lgkmcnt(0)" ::: "memory");  // wave-local LDS exchange
      f4v acc[5];
      #pragma unroll
      for (int t=0;t<5;t++) acc[t] = (f4v){0.f,0.f,0.f,0.f};
      #pragma unroll
      for (int kh=0;kh<2;kh++){
        s8v af = *(const s8v*)(hw + e*72 + kh*32 + q*8);
        #pragma unroll
        for (int t=0;t<5;t++)
          acc[t] = __builtin_amdgcn_mfma_f32_16x16x32_bf16(af, bfr[t][kh], acc[t], 0,0,0);
      }
      // C layout col=u, row=q*4+r -> LDS planes
      #pragma unroll
      for (int r=0;r<4;r++){
        int er2 = tbase + q*4 + r;
        if (er2 < end){
          int le = er2 - sbeg;
          #pragma unroll
          for (int t=0;t<5;t++) wp[t][le][u] = f2bf(acc[t][r]);
        }
      }
    }
    __syncthreads();
    // ---- phase B: reduce this sweep's portion of receiver pr ----
    int lo = rbeg > sbeg ? rbeg : sbeg;
    int hi = rend < sbeg + EPS ? rend : sbeg + EPS;
    if (lo < hi){
      int c = wsub*4 + q;
      int off0 = (lo - rbeg) & 7;
      int st = (c - off0) & 7;
      for (int rank = lo + st; rank < hi; rank += 8){
        int li = rank - sbeg;
        f4v y = *(const f4v*)yb[li];
        float Y0=y[0], Yv0=y[1], Yv1=y[2], Yv2=y[3];
        int snd = sn[li];
        float w0=bf2f(wp[0][li][u]), w1=bf2f(wp[1][li][u]), w2=bf2f(wp[2][li][u]);
        float w3=bf2f(wp[3][li][u]), w4=bf2f(wp[4][li][u]);
        u16x4 sv = *(const u16x4*)(sv16 + ((size_t)snd*16 + u)*4);
        float xs=bf2f(sv[0]), x0=bf2f(sv[1]), x1=bf2f(sv[2]), x2=bf2f(sv[3]);
        As0 += w0*xs*Y0;
        As1 += w1*(x0*Yv0 + x1*Yv1 + x2*Yv2);
        float t1 = w2*xs;  Av00 += t1*Yv0; Av01 += t1*Yv1; Av02 += t1*Yv2;
        float t2 = w3*Y0;  Av10 += t2*x0;  Av11 += t2*x1;  Av12 += t2*x2;
        Av20 += w4*(x1*Yv2 - x2*Yv1);
        Av21 += w4*(x2*Yv0 - x0*Yv2);
        Av22 += w4*(x0*Yv1 - x1*Yv0);
      }
    }
    __syncthreads();   // protect LDS before next sweep's phase A
  }
  // butterfly reduce across q (lane xor 16, 32)
  #define RED2(x) { x += __shfl_xor(x,16); x += __shfl_xor(x,32); }
  RED2(As0) RED2(As1)
  RED2(Av00) RED2(Av01) RED2(Av02)
  RED2(Av10) RED2(Av11) RED2(Av12)
  RED2(Av20) RED2(Av21) RED2(Av22)
  #undef RED2
  if (q == 0){
    float* pp = part[wid];
    pp[u]=As0;      pp[16+u]=As1;
    pp[32+u]=Av00;  pp[48+u]=Av10;  pp[64+u]=Av20;
    pp[80+u]=Av01;  pp[96+u]=Av11;  pp[112+u]=Av21;
    pp[128+u]=Av02; pp[144+u]=Av12; pp[160+u]=Av22;
  }
  __syncthreads();
  for (int i = tid; i < 352; i += 256){
    int pr2 = i / 176, idx = i - pr2*176;
    accbuf[(size_t)(r0n + pr2)*176 + idx] = part[pr2*2][idx] + part[pr2*2+1][idx];
  }
}

// epilogue: dense per-node output, 16 threads per node, LDS-staged accumulators.
__global__ void __launch_bounds__(256) pass2_epilogue(
    const float* __restrict__ accbuf, const float* __restrict__ wbuf,
    const void* __restrict__ ns_g, const void* __restrict__ nv_g,
    const int* __restrict__ species, void* __restrict__ out,
    const int* __restrict__ flag){
  __shared__ float sb[16*176 + 16*16 + 16*48];   // bins | ns | vin
  int tid = threadIdx.x;
  int isf = *flag;
  int n0 = blockIdx.x*16;
  int rem = N_NODES - n0;
  int nblk = rem < 16 ? rem : 16;
  {
    int tot = nblk*176;
    const float* src = accbuf + (size_t)n0*176;
    for (int i=tid; i<tot; i+=256) sb[i] = src[i];
    float* nsb = sb + 2816;
    for (int i=tid; i<nblk*16; i+=256)
      nsb[i] = ldx(ns_g, (long long)n0*16 + i, isf);
    float* vinb = sb + 2816 + 256;
    for (int i=tid; i<nblk*48; i+=256)
      vinb[i] = ldx(nv_g, (long long)n0*48 + i, isf);
  }
  __syncthreads();
  int g = tid >> 4, u = tid & 15;
  if (g >= nblk) return;
  int nn = n0 + g;
  const float* bin  = sb + g*176;
  const float* nsb  = sb + 2816 + g*16;
  const float* vinb = sb + 2816 + 256 + g*48;
  int sp = species[nn];
  const float* wos = wbuf + WB_WOS;
  const float* scs = wbuf + WB_SCS + sp*512;
  const float* wov = wbuf + WB_WOV;
  const float* scv = wbuf + WB_SCV + sp*256;
  float p0 = 0.f, p1 = 0.f;
  #pragma unroll
  for (int j=0;j<32;j++){
    float a = bin[j]*0.25f;
    p0 += a*wos[j*32+u];
    p1 += a*wos[j*32+16+u];
  }
  #pragma unroll
  for (int j=0;j<16;j++){
    float nu = nsb[j];
    p0 += nu*scs[j*32+u];
    p1 += nu*scs[j*32+16+u];
  }
  float gate = sigmoidf_(p1);
  float os = p0*sigmoidf_(p0) + nsb[u];
  float pv0, pv1, pv2;
  {
    float a0=0.f, a1=0.f, a2=0.f;
    #pragma unroll
    for (int j=0;j<48;j++){
      float wv = wov[j*16+u];
      a0 += bin[32 + 0*48 + j]*0.25f*wv;
      a1 += bin[32 + 1*48 + j]*0.25f*wv;
      a2 += bin[32 + 2*48 + j]*0.25f*wv;
    }
    #pragma unroll
    for (int j=0;j<16;j++){
      float sv = scv[j*16+u];
      a0 += vinb[j*3+0]*sv;
      a1 += vinb[j*3+1]*sv;
      a2 += vinb[j*3+2]*sv;
    }
    pv0 = a0*gate + vinb[u*3+0];
    pv1 = a1*gate + vinb[u*3+1];
    pv2 = a2*gate + vinb[u*3+2];
  }
  if (isf){
    float* orow = (float*)out + (size_t)nn*64;
    orow[u] = os;
    orow[16 + u*3 + 0] = pv0;
    orow[16 + u*3 + 1] = pv1;
    orow[16 + u*3 + 2] = pv2;
  } else {
    u16* orow = (u16*)out + (size_t)nn*64;
    orow[u] = f2bf(os);
    orow[16 + u*3 + 0] = f2bf(pv0);
    orow[16 + u*3 + 1] = f2bf(pv1);
    orow[16 + u*3 + 2] = f2bf(pv2);
  }
}

extern "C" void kernel_launch(void* const* d_in, const int* in_sizes, int n_in,
                              void* d_out, int out_size, void* d_ws, size_t ws_size,
                              hipStream_t stream){
  const void* node_scalars = d_in[0];
  const void* node_vectors = d_in[1];
  const void* edge_sh      = d_in[2];
  const void* radial_emb   = d_in[3];
  const int* senders      = (const int*)d_in[4];
  const int* receivers    = (const int*)d_in[5];
  const int* species      = (const int*)d_in[6];
  const void* W_in_s  = d_in[7];
  const void* W_in_v  = d_in[8];
  const void* mlp_w1  = d_in[9];
  const void* mlp_b1  = d_in[10];
  const void* mlp_w2  = d_in[11];
  const void* W_out_s = d_in[12];
  const void* W_out_v = d_in[13];
  const void* sc_s    = d_in[14];
  const void* sc_v    = d_in[15];

  float* wsf  = (float*)d_ws;
  int*   wsi  = (int*)d_ws;
  u32*   wsu  = (u32*)d_ws;
  float* wbuf = wsf;
  u16*   sv16 = (u16*)(wsu + OFF_SV16);
  int*   bcnt = wsi + IDX_BCNT;
  int*   bof2 = wsi + IDX_BOF2;
  int*   bcur = wsi + IDX_BCUR;
  int*   offs = wsi + IDX_OFFS;
  int*   buck = wsi + IDX_BUCK;
  u32*   eeid = wsu + IDX_EEID;
  u16*   er16 = (u16*)(wsu + OFF_ER16);
  u32*   rec  = wsu + OFF_REC;
  float* accb = wsf + ACC_OFF;
  int*   flag = (int*)(wbuf + WB_FLAG);

  detect_dtype<<<1,64,0,stream>>>((const u32*)radial_emb, flag);
  hipMemsetAsync(bcnt, 0, NBINS*sizeof(int), stream);
  prep_weights<<<1,256,0,stream>>>(mlp_w1, mlp_b1, mlp_w2, W_in_s, W_in_v,
                                   W_out_s, W_out_v, sc_s, sc_v, wbuf, flag);
  node_pre<<<N_NODES/16,256,0,stream>>>(node_scalars, node_vectors, wbuf,
                                        sv16, flag);
  pack_edges<<<(N_EDGES+255)/256,256,0,stream>>>(radial_emb, edge_sh, senders,
                                                 rec, flag);
  bin_count<<<NBB,256,0,stream>>>(receivers, bcnt);
  bin_scan<<<1,256,0,stream>>>(bcnt, bof2, bcur, offs);
  bin_scatter<<<NBB,256,0,stream>>>(receivers, bcur, eeid, er16);
  bin_finalize<<<NBINS,256,0,stream>>>(eeid, er16, bof2, bcnt, offs, buck);
  pass_fused<<<N_NODES/2,256,0,stream>>>(buck, offs, rec, wbuf, sv16, accb, flag);
  pass2_epilogue<<<(N_NODES+15)/16,256,0,stream>>>(accb, wbuf, node_scalars,
                                                   node_vectors, species,
                                                   d_out, flag);
}

// Round 13
// 371.627 us; speedup vs baseline: 1.2627x; 1.2627x over previous
//
#include <hip/hip_runtime.h>
#include <hip/hip_bf16.h>

typedef unsigned short u16;
typedef unsigned int   u32;
typedef _Float16 h2 __attribute__((ext_vector_type(2)));
typedef short s8v __attribute__((ext_vector_type(8)));
typedef float f4v __attribute__((ext_vector_type(4)));
typedef u16 u16x4 __attribute__((ext_vector_type(4)));

#define N_NODES 50000
#define N_EDGES 800000
#define NCH   2
#define RPC   25000      // receivers per chunk
#define CHMAX 409600     // max edges per chunk (mean 400k, +21 sigma)

// binned bucket construction
#define RPB   250        // receivers per bin (chunk boundary 25000 = bin 100, aligned)
#define NBINS 200
#define EPB   4096       // edges per block in binning kernels
#define NBB   ((N_EDGES+EPB-1)/EPB)   // 196

// ---- ws layout (u32 units), total ~26.4M u32 = 105.5 MB ----
#define WB_W1H  0        // [64][4] u32 half2 (fp16 pairs of W1 columns)
#define WB_B1   256      // [64] f32
#define WB_W2F  320      // 5120 bf16 = 2560 u32, MFMA B-frag layout
#define WB_WINS 2880
#define WB_WINV 3136
#define WB_WOS  3392
#define WB_WOV  4416
#define WB_SCS  5184
#define WB_SCV  7232
#define WB_FLAG 8256
#define OFF_SV16 8260    // [50000][16][4] u16 (xs,x0,x1,x2)
#define IDX_BCNT 1608260 // 200 ints
#define IDX_BOF2 1608516 // 200 ints
#define IDX_BCUR 1608772 // 200 ints
#define IDX_OFFS 1658260 // 50001 ints
#define IDX_BUCK 1758262 // 800,000 int
#define IDX_EEID 2558264 // 800,000 u32 (bin-grouped edge ids)
#define OFF_ER16 3358264 // 800,000 u16 (bin-grouped receivers)
#define OFF_WPA  3758264 // [CHMAX][16] u16x4 (w0..w3) = 13,107,200 u32
#define OFF_WPB  16865464 // [CHMAX][16] u16 (w4) = 3,276,800 u32
#define OFF_YB   20142264 // [CHMAX] f4v (Y0,Yv0,Yv1,Yv2 f32, rank order) = 1,638,400 u32
#define OFF_SND  21780664 // [CHMAX] u16 (sender, rank order) = 204,800 u32
#define ACC_OFF  21985464 // 25,000 x 176 f32 per-chunk accumulators

__device__ __forceinline__ float bf2f(u16 v){
  union { u32 u; float f; } x; x.u = ((u32)v) << 16; return x.f;
}
__device__ __forceinline__ u16 f2bf(float f){
  u32 u = __float_as_uint(f);
  u32 lsb = (u >> 16) & 1u;
  u32 r = u + 0x7fffu + lsb;
  return (u16)(r >> 16);
}
__device__ __forceinline__ float ldx(const void* p, long long i, int isf){
  return isf ? ((const float*)p)[i] : bf2f(((const u16*)p)[i]);
}
__device__ __forceinline__ u32 pkh2(float a, float b){
  union { u32 u; h2 v; } x; x.v.x = (_Float16)a; x.v.y = (_Float16)b; return x.u;
}
__device__ __forceinline__ float dot2(h2 a, u32 w, float c){
  union { u32 u; h2 v; } x; x.u = w;
#if __has_builtin(__builtin_amdgcn_fdot2)
  return __builtin_amdgcn_fdot2(a, x.v, c, false);
#else
  return c + (float)a.x*(float)x.v.x + (float)a.y*(float)x.v.y;
#endif
}
__device__ __forceinline__ float sigmoidf_(float x){ return 1.f/(1.f + __expf(-x)); }

__global__ void detect_dtype(const u32* __restrict__ remb_raw, int* __restrict__ flag){
  int t = threadIdx.x;           // 64 lanes, one word each
  u32 w = remb_raw[t];
  u32 lo = w & 0xffffu, hi = w >> 16;
  int okl = ((lo & 0x8000u) == 0) && (((lo >> 7) & 0xffu) <= 126u);
  int okh = ((hi & 0x8000u) == 0) && (((hi >> 7) & 0xffu) <= 126u);
  unsigned long long bad = __ballot(!(okl && okh));
  if (t == 0) *flag = (bad != 0ull) ? 1 : 0;
}

__global__ void prep_weights(const void* __restrict__ w1, const void* __restrict__ b1g,
                             const void* __restrict__ w2, const void* __restrict__ wins,
                             const void* __restrict__ winv, const void* __restrict__ wos,
                             const void* __restrict__ wov, const void* __restrict__ scs,
                             const void* __restrict__ scv, float* __restrict__ wbuf,
                             const int* __restrict__ flag){
  int t = threadIdx.x;
  int isf = *flag;
  u32* w1h  = (u32*)(wbuf + WB_W1H);
  u16* w2f  = (u16*)(wbuf + WB_W2F);
  for (int idx=t; idx<256;  idx+=256){
    int j = idx>>2, ip = idx&3;
    w1h[idx] = pkh2(ldx(w1, (2*ip)*64+j, isf), ldx(w1, (2*ip+1)*64+j, isf));
  }
  for (int idx=t; idx<64;   idx+=256){ wbuf[WB_B1+idx]  = ldx(b1g, idx, isf); }
  // MFMA B-frag layout for 16x16x32 bf16: lane holds B[k=(lane>>4)*8+j][n=lane&15]
  for (int idx=t; idx<5120; idx+=256){
    int tt = idx >> 10;           // N-tile 0..4
    int rem = idx & 1023;
    int kh = rem >> 9;            // K-half 0..1
    int rem2 = rem & 511;
    int ln = rem2 >> 3, j = rem2 & 7;
    int k = kh*32 + (ln>>4)*8 + j;
    int o = tt*16 + (ln&15);
    w2f[idx] = f2bf(ldx(w2, (long long)k*80 + o, isf));
  }
  for (int idx=t; idx<256;  idx+=256){ wbuf[WB_WINS+idx] = ldx(wins, idx, isf); }
  for (int idx=t; idx<256;  idx+=256){ wbuf[WB_WINV+idx] = ldx(winv, idx, isf); }
  for (int idx=t; idx<1024; idx+=256){ wbuf[WB_WOS+idx]  = ldx(wos, idx, isf); }
  for (int idx=t; idx<768;  idx+=256){ wbuf[WB_WOV+idx]  = ldx(wov, idx, isf); }
  for (int idx=t; idx<2048; idx+=256){ wbuf[WB_SCS+idx]  = ldx(scs, idx, isf); }
  for (int idx=t; idx<1024; idx+=256){ wbuf[WB_SCV+idx]  = ldx(scv, idx, isf); }
}

// node_pre v2: 256 threads / 16 nodes per block, 16 threads per node.
// LDS-staged inputs + weights; 4 accumulators per thread (low VGPR, high occupancy).
// Accumulation order over j matches the original u-ascending loop -> bit-identical.
__global__ void __launch_bounds__(256) node_pre(
    const void* __restrict__ ns_g, const void* __restrict__ nv_g,
    const float* __restrict__ wbuf, u16* __restrict__ sv16,
    const int* __restrict__ flag){
  __shared__ float A[16][16];     // [node][u] scalars
  __shared__ float B[16][48];     // [node][u*3+c] vectors
  __shared__ float wsl[256], wvl[256];
  int tid = threadIdx.x;
  int isf = *flag;
  int n0 = blockIdx.x*16;         // 3125*16 = 50000 exact
  for (int i=tid;i<256;i+=256){ wsl[i]=wbuf[WB_WINS+i]; wvl[i]=wbuf[WB_WINV+i]; }
  for (int i=tid;i<256;i+=256) A[i>>4][i&15] = ldx(ns_g,(long long)n0*16+i,isf);
  for (int i=tid;i<768;i+=256) B[i/48][i%48] = ldx(nv_g,(long long)n0*48+i,isf);
  __syncthreads();
  int g = tid>>4, u = tid&15;
  float s=0.f, v0=0.f, v1=0.f, v2=0.f;
  #pragma unroll
  for (int j=0;j<16;j++){
    s  += A[g][j]*wsl[j*16+u];
    float wv = wvl[j*16+u];
    v0 += B[g][j*3+0]*wv;
    v1 += B[g][j*3+1]*wv;
    v2 += B[g][j*3+2]*wv;
  }
  u16x4 pk;
  pk[0]=f2bf(s); pk[1]=f2bf(v0); pk[2]=f2bf(v1); pk[3]=f2bf(v2);
  ((u16x4*)sv16)[(size_t)(n0+g)*16 + u] = pk;
}

// ---- binned bucket construction ----
__global__ void __launch_bounds__(256) bin_count(const int* __restrict__ receivers,
                                                 int* __restrict__ bcnt){
  __shared__ int lcnt[NBINS];
  int t = threadIdx.x;
  for (int i=t;i<NBINS;i+=256) lcnt[i]=0;
  __syncthreads();
  int base = blockIdx.x*EPB;
  for (int i=t;i<EPB;i+=256){
    int e = base+i;
    if (e<N_EDGES) atomicAdd(&lcnt[receivers[e]/RPB],1);
  }
  __syncthreads();
  for (int i=t;i<NBINS;i+=256) if (lcnt[i]) atomicAdd(&bcnt[i], lcnt[i]);
}

__global__ void bin_scan(const int* __restrict__ bcnt, int* __restrict__ binoff,
                         int* __restrict__ bincur, int* __restrict__ offs){
  __shared__ int lds[NBINS];
  int t=threadIdx.x;
  if (t<NBINS) lds[t]=bcnt[t];
  __syncthreads();
  for (int off=1; off<NBINS; off<<=1){
    int v = (t<NBINS && t>=off)? lds[t-off] : 0;
    __syncthreads();
    if (t<NBINS) lds[t]+=v;
    __syncthreads();
  }
  if (t<NBINS){ int ex = lds[t]-bcnt[t]; binoff[t]=ex; bincur[t]=ex; }
  if (t==0) offs[N_NODES] = N_EDGES;
}

__global__ void __launch_bounds__(256) bin_scatter(const int* __restrict__ receivers,
                 int* __restrict__ bincur, u32* __restrict__ eeid, u16* __restrict__ er){
  __shared__ int lcnt[NBINS], loff[NBINS], lcur[NBINS], gbase[NBINS];
  __shared__ u32 seid[EPB];
  __shared__ u16 sr[EPB];
  int t = threadIdx.x;
  for (int i=t;i<NBINS;i+=256) lcnt[i]=0;
  __syncthreads();
  int base = blockIdx.x*EPB;
  int r_[16];
  #pragma unroll
  for (int k=0;k<16;k++){
    int e = base + t + k*256;
    r_[k] = (e<N_EDGES)? receivers[e] : -1;
    if (r_[k]>=0) atomicAdd(&lcnt[r_[k]/RPB],1);
  }
  __syncthreads();
  if (t<NBINS) loff[t]=lcnt[t];
  __syncthreads();
  for (int off=1; off<NBINS; off<<=1){
    int v=(t<NBINS&&t>=off)?loff[t-off]:0;
    __syncthreads();
    if (t<NBINS) loff[t]+=v;
    __syncthreads();
  }
  if (t<NBINS){
    int ex=loff[t]-lcnt[t]; loff[t]=ex; lcur[t]=ex;
    gbase[t] = lcnt[t] ? atomicAdd(&bincur[t], lcnt[t]) : 0;
  }
  __syncthreads();
  #pragma unroll
  for (int k=0;k<16;k++){
    if (r_[k]>=0){
      int b=r_[k]/RPB;
      int p=atomicAdd(&lcur[b],1);
      seid[p]=(u32)(base + t + k*256);
      sr[p]=(u16)r_[k];
    }
  }
  __syncthreads();
  int rem = N_EDGES - base;
  int tot = rem < EPB ? rem : EPB;
  for (int i=t;i<tot;i+=256){
    int b = sr[i]/RPB;
    int dst = gbase[b] + (i - loff[b]);
    eeid[dst]=seid[i]; er[dst]=sr[i];
  }
}

__global__ void __launch_bounds__(256) bin_finalize(const u32* __restrict__ eeid,
        const u16* __restrict__ er, const int* __restrict__ binoff,
        const int* __restrict__ bcnt, int* __restrict__ offs, int* __restrict__ bucket){
  __shared__ int deg[RPB], pfx[RPB], lcur[RPB];
  int b=blockIdx.x, t=threadIdx.x;
  int beg=binoff[b], cnt=bcnt[b];
  for (int i=t;i<RPB;i+=256) deg[i]=0;
  __syncthreads();
  int r0=b*RPB;
  for (int i=t;i<cnt;i+=256) atomicAdd(&deg[er[beg+i]-r0],1);
  __syncthreads();
  if (t<RPB) pfx[t]=deg[t];
  __syncthreads();
  for (int off=1; off<RPB; off<<=1){
    int v=(t<RPB&&t>=off)?pfx[t-off]:0;
    __syncthreads();
    if (t<RPB) pfx[t]+=v;
    __syncthreads();
  }
  if (t<RPB){
    int ex=pfx[t]-deg[t]; pfx[t]=ex; lcur[t]=ex;
    offs[r0+t]=beg+ex;
  }
  __syncthreads();
  for (int i=t;i<cnt;i+=256){
    int rr = er[beg+i]-r0;
    int k = atomicAdd(&lcur[rr],1);
    bucket[beg+k] = (int)eeid[beg+i];
  }
}

// pass1: per chunk, compute w[80] per edge via MFMA; wave = 16 edges.
// Outputs (all chunk-local rank order):
//   wpA [edge][u] u16x4 = w0..w3 bf16; wpB [edge][u] u16 = w4 bf16
//   ybf [edge] f4v = edge_sh (f32, exact); snd16 [edge] u16 = sender
__global__ void __launch_bounds__(256) pass1_w(
    const int* __restrict__ bucket, const int* __restrict__ offs,
    const void* __restrict__ remb, const void* __restrict__ edge_sh,
    const int* __restrict__ senders, const float* __restrict__ wbuf,
    u16* __restrict__ wpA, u16* __restrict__ wpB,
    float* __restrict__ ybf, u16* __restrict__ snd16,
    int rlo, const int* __restrict__ flag){
  __shared__ u16 hlds[4*16*72];        // 4 waves x 16 edges x 64 h (+8 pad)
  int tid = threadIdx.x;
  int lane = tid & 63, wid = tid >> 6;
  int isf = *flag;
  int chunkBeg = offs[rlo], chunkEnd = offs[rlo + RPC];
  int r0e = chunkBeg + (blockIdx.x*4 + wid)*16;
  if (r0e >= chunkEnd) return;         // whole-wave exit; no __syncthreads in kernel
  u16* hw = hlds + wid*(16*72);
  int e = lane & 15, q = lane >> 4;

  // ---- h for edge (r0e+e), j = q*16 .. q*16+15 ----
  int er = r0e + e;
  int eid = (er < chunkEnd) ? bucket[er] : 0;
  // rank-order side tables (one writer per edge: q==0 lanes)
  if (q == 0 && er < chunkEnd){
    size_t widx = (size_t)(er - chunkBeg);
    snd16[widx] = (u16)senders[eid];
    f4v y;
    if (isf){
      y = ((const f4v*)edge_sh)[eid];
    } else {
      u16x4 yb = ((const u16x4*)edge_sh)[eid];
      y[0]=bf2f(yb[0]); y[1]=bf2f(yb[1]); y[2]=bf2f(yb[2]); y[3]=bf2f(yb[3]);
    }
    ((f4v*)ybf)[widx] = y;
  }
  float re[8];
  if (isf){
    f4v ra = ((const f4v*)remb)[(size_t)eid*2];
    f4v rb = ((const f4v*)remb)[(size_t)eid*2+1];
    re[0]=ra[0]; re[1]=ra[1]; re[2]=ra[2]; re[3]=ra[3];
    re[4]=rb[0]; re[5]=rb[1]; re[6]=rb[2]; re[7]=rb[3];
  } else {
    s8v r8 = ((const s8v*)remb)[eid];
    #pragma unroll
    for (int i=0;i<8;i++) re[i] = bf2f((u16)r8[i]);
  }
  h2 reh[4];
  #pragma unroll
  for (int ip=0;ip<4;ip++){ reh[ip].x=(_Float16)re[2*ip]; reh[ip].y=(_Float16)re[2*ip+1]; }
  const u32* w1h = (const u32*)(wbuf + WB_W1H);
  const float* b1 = wbuf + WB_B1;
  #pragma unroll
  for (int jj=0;jj<16;jj++){
    int j = q*16 + jj;
    float a = b1[j];
    #pragma unroll
    for (int ip=0;ip<4;ip++) a = dot2(reh[ip], w1h[j*4+ip], a);
    a = a * sigmoidf_(a);
    hw[e*72 + j] = f2bf(a);
  }
  asm volatile("s_waitcnt lgkmcnt(0)" ::: "memory");  // wave-local LDS exchange

  // ---- B-frags (W2), 10 x 16B, coalesced, held in VGPRs ----
  const u16* w2f = (const u16*)(wbuf + WB_W2F);
  s8v bfr[5][2];
  #pragma unroll
  for (int t=0;t<5;t++)
    #pragma unroll
    for (int kh=0;kh<2;kh++)
      bfr[t][kh] = *(const s8v*)(w2f + ((t*2+kh)*64 + lane)*8);

  f4v acc[5];
  #pragma unroll
  for (int t=0;t<5;t++) acc[t] = (f4v){0.f,0.f,0.f,0.f};
  #pragma unroll
  for (int kh=0;kh<2;kh++){
    // A-frag: lane holds h[m=lane&15][k=kh*32 + q*8 + j]
    s8v af = *(const s8v*)(hw + e*72 + kh*32 + q*8);
    #pragma unroll
    for (int t=0;t<5;t++)
      acc[t] = __builtin_amdgcn_mfma_f32_16x16x32_bf16(af, bfr[t][kh], acc[t], 0,0,0);
  }
  // ---- store: C layout col=lane&15 (=u), row=q*4+reg (=edge in tile) ----
  int n = lane & 15;
  #pragma unroll
  for (int r=0;r<4;r++){
    int er2 = r0e + q*4 + r;
    if (er2 < chunkEnd){
      size_t widx = (size_t)(er2 - chunkBeg);
      u16x4 pk4;
      pk4[0]=f2bf(acc[0][r]); pk4[1]=f2bf(acc[1][r]);
      pk4[2]=f2bf(acc[2][r]); pk4[3]=f2bf(acc[3][r]);
      ((u16x4*)wpA)[widx*16 + n] = pk4;
      wpB[widx*16 + n] = f2bf(acc[4][r]);
    }
  }
}

// pass2a: 8-way edge parallelism per receiver (2 waves/receiver, block = 2 receivers).
// All per-edge inputs are rank-ordered streams (wpA/wpB/ybf/snd16); only sv16 is a
// gather, and its chain is depth 1 (snd16 is streamed). Intra-wave shfl_xor reduce
// over q, then LDS combine across the wave pair.
__global__ void __launch_bounds__(256, 4) pass2_reduce(
    const int* __restrict__ offs,
    const u16* __restrict__ sv16, const u16* __restrict__ wpA,
    const u16* __restrict__ wpB, const float* __restrict__ ybf,
    const u16* __restrict__ snd16, float* __restrict__ accbuf,
    int rlo){
  __shared__ float part[4][176];
  int tid = threadIdx.x;
  int lane = tid & 63, wid = tid >> 6;
  int u = lane & 15, q = lane >> 4;
  int pr = wid >> 1;                 // receiver slot within block (0..1)
  int wsub = wid & 1;                // wave within the pair
  int r = rlo + blockIdx.x*2 + pr;   // grid = RPC/2, exact cover
  int chunkBeg = offs[rlo];
  int beg = offs[r], end = offs[r+1];
  float As0=0.f,As1=0.f;
  float Av00=0.f,Av01=0.f,Av02=0.f, Av10=0.f,Av11=0.f,Av12=0.f, Av20=0.f,Av21=0.f,Av22=0.f;
  auto body = [&](int rank){
    size_t li = (size_t)(rank - chunkBeg);
    f4v y = ((const f4v*)ybf)[li];
    float Y0=y[0], Yv0=y[1], Yv1=y[2], Yv2=y[3];
    int snd = snd16[li];
    u16x4 wv = ((const u16x4*)wpA)[li*16 + u];
    float w0=bf2f(wv[0]), w1=bf2f(wv[1]), w2=bf2f(wv[2]), w3=bf2f(wv[3]);
    float w4=bf2f(wpB[li*16 + u]);
    u16x4 sv = *(const u16x4*)(sv16 + ((size_t)snd*16 + u)*4);
    float xs=bf2f(sv[0]), x0=bf2f(sv[1]), x1=bf2f(sv[2]), x2=bf2f(sv[3]);
    As0 += w0*xs*Y0;
    As1 += w1*(x0*Yv0 + x1*Yv1 + x2*Yv2);
    float t1 = w2*xs;  Av00 += t1*Yv0; Av01 += t1*Yv1; Av02 += t1*Yv2;
    float t2 = w3*Y0;  Av10 += t2*x0;  Av11 += t2*x1;  Av12 += t2*x2;
    Av20 += w4*(x1*Yv2 - x2*Yv1);
    Av21 += w4*(x2*Yv0 - x0*Yv2);
    Av22 += w4*(x0*Yv1 - x1*Yv0);
  };
  int rank = beg + wsub*4 + q;
  for (; rank + 8 < end; rank += 16){ body(rank); body(rank+8); }
  if (rank < end) body(rank);
  // butterfly reduce across q (lane xor 16, 32) -> per-wave sums on all lanes
  #define RED2(x) { x += __shfl_xor(x,16); x += __shfl_xor(x,32); }
  RED2(As0) RED2(As1)
  RED2(Av00) RED2(Av01) RED2(Av02)
  RED2(Av10) RED2(Av11) RED2(Av12)
  RED2(Av20) RED2(Av21) RED2(Av22)
  #undef RED2
  // layout: [0,16)=As0  [16,32)=As1  32 + c*48 + p*16 + u = Av[p][c]
  if (q == 0){
    float* pp = part[wid];
    pp[u]=As0;      pp[16+u]=As1;
    pp[32+u]=Av00;  pp[48+u]=Av10;  pp[64+u]=Av20;
    pp[80+u]=Av01;  pp[96+u]=Av11;  pp[112+u]=Av21;
    pp[128+u]=Av02; pp[144+u]=Av12; pp[160+u]=Av22;
  }
  __syncthreads();
  for (int i = tid; i < 352; i += 256){
    int pr2 = i / 176, idx = i - pr2*176;
    int rr = blockIdx.x*2 + pr2;
    accbuf[(size_t)rr*176 + idx] = part[pr2*2][idx] + part[pr2*2+1][idx];
  }
}

// pass2b: dense per-node epilogue, 16 threads per node, LDS-staged accumulators.
__global__ void __launch_bounds__(256) pass2_epilogue(
    const float* __restrict__ accbuf, const float* __restrict__ wbuf,
    const void* __restrict__ ns_g, const void* __restrict__ nv_g,
    const int* __restrict__ species, void* __restrict__ out,
    int rlo, const int* __restrict__ flag){
  __shared__ float sb[16*176 + 16*16 + 16*48];   // bins | ns | vin
  int tid = threadIdx.x;
  int isf = *flag;
  int n0 = rlo + blockIdx.x*16;
  int rem = rlo + RPC - n0;
  int nblk = rem < 16 ? rem : 16;
  {
    int tot = nblk*176;
    const float* src = accbuf + (size_t)(n0 - rlo)*176;
    for (int i=tid; i<tot; i+=256) sb[i] = src[i];
    float* nsb = sb + 2816;
    for (int i=tid; i<nblk*16; i+=256)
      nsb[i] = ldx(ns_g, (long long)n0*16 + i, isf);
    float* vinb = sb + 2816 + 256;
    for (int i=tid; i<nblk*48; i+=256)
      vinb[i] = ldx(nv_g, (long long)n0*48 + i, isf);
  }
  __syncthreads();
  int g = tid >> 4, u = tid & 15;
  if (g >= nblk) return;
  int nn = n0 + g;
  const float* bin  = sb + g*176;
  const float* nsb  = sb + 2816 + g*16;
  const float* vinb = sb + 2816 + 256 + g*48;
  int sp = species[nn];
  const float* wos = wbuf + WB_WOS;
  const float* scs = wbuf + WB_SCS + sp*512;
  const float* wov = wbuf + WB_WOV;
  const float* scv = wbuf + WB_SCV + sp*256;
  float p0 = 0.f, p1 = 0.f;
  #pragma unroll
  for (int j=0;j<32;j++){
    float a = bin[j]*0.25f;
    p0 += a*wos[j*32+u];
    p1 += a*wos[j*32+16+u];
  }
  #pragma unroll
  for (int j=0;j<16;j++){
    float nu = nsb[j];
    p0 += nu*scs[j*32+u];
    p1 += nu*scs[j*32+16+u];
  }
  float gate = sigmoidf_(p1);
  float os = p0*sigmoidf_(p0) + nsb[u];
  float pv0, pv1, pv2;
  {
    float a0=0.f, a1=0.f, a2=0.f;
    #pragma unroll
    for (int j=0;j<48;j++){
      float wv = wov[j*16+u];
      a0 += bin[32 + 0*48 + j]*0.25f*wv;
      a1 += bin[32 + 1*48 + j]*0.25f*wv;
      a2 += bin[32 + 2*48 + j]*0.25f*wv;
    }
    #pragma unroll
    for (int j=0;j<16;j++){
      float sv = scv[j*16+u];
      a0 += vinb[j*3+0]*sv;
      a1 += vinb[j*3+1]*sv;
      a2 += vinb[j*3+2]*sv;
    }
    pv0 = a0*gate + vinb[u*3+0];
    pv1 = a1*gate + vinb[u*3+1];
    pv2 = a2*gate + vinb[u*3+2];
  }
  if (isf){
    float* orow = (float*)out + (size_t)nn*64;
    orow[u] = os;
    orow[16 + u*3 + 0] = pv0;
    orow[16 + u*3 + 1] = pv1;
    orow[16 + u*3 + 2] = pv2;
  } else {
    u16* orow = (u16*)out + (size_t)nn*64;
    orow[u] = f2bf(os);
    orow[16 + u*3 + 0] = f2bf(pv0);
    orow[16 + u*3 + 1] = f2bf(pv1);
    orow[16 + u*3 + 2] = f2bf(pv2);
  }
}

extern "C" void kernel_launch(void* const* d_in, const int* in_sizes, int n_in,
                              void* d_out, int out_size, void* d_ws, size_t ws_size,
                              hipStream_t stream){
  const void* node_scalars = d_in[0];
  const void* node_vectors = d_in[1];
  const void* edge_sh      = d_in[2];
  const void* radial_emb   = d_in[3];
  const int* senders      = (const int*)d_in[4];
  const int* receivers    = (const int*)d_in[5];
  const int* species      = (const int*)d_in[6];
  const void* W_in_s  = d_in[7];
  const void* W_in_v  = d_in[8];
  const void* mlp_w1  = d_in[9];
  const void* mlp_b1  = d_in[10];
  const void* mlp_w2  = d_in[11];
  const void* W_out_s = d_in[12];
  const void* W_out_v = d_in[13];
  const void* sc_s    = d_in[14];
  const void* sc_v    = d_in[15];

  float* wsf  = (float*)d_ws;
  int*   wsi  = (int*)d_ws;
  u32*   wsu  = (u32*)d_ws;
  float* wbuf = wsf;
  u16*   sv16 = (u16*)(wsu + OFF_SV16);
  int*   bcnt = wsi + IDX_BCNT;
  int*   bof2 = wsi + IDX_BOF2;
  int*   bcur = wsi + IDX_BCUR;
  int*   offs = wsi + IDX_OFFS;
  int*   buck = wsi + IDX_BUCK;
  u32*   eeid = wsu + IDX_EEID;
  u16*   er16 = (u16*)(wsu + OFF_ER16);
  u16*   wpA  = (u16*)(wsu + OFF_WPA);
  u16*   wpB  = (u16*)(wsu + OFF_WPB);
  float* ybf  = wsf + OFF_YB;
  u16*   snd16= (u16*)(wsu + OFF_SND);
  float* accb = wsf + ACC_OFF;
  int*   flag = (int*)(wbuf + WB_FLAG);

  detect_dtype<<<1,64,0,stream>>>((const u32*)radial_emb, flag);
  hipMemsetAsync(bcnt, 0, NBINS*sizeof(int), stream);
  prep_weights<<<1,256,0,stream>>>(mlp_w1, mlp_b1, mlp_w2, W_in_s, W_in_v,
                                   W_out_s, W_out_v, sc_s, sc_v, wbuf, flag);
  node_pre<<<N_NODES/16,256,0,stream>>>(node_scalars, node_vectors, wbuf,
                                        sv16, flag);
  bin_count<<<NBB,256,0,stream>>>(receivers, bcnt);
  bin_scan<<<1,256,0,stream>>>(bcnt, bof2, bcur, offs);
  bin_scatter<<<NBB,256,0,stream>>>(receivers, bcur, eeid, er16);
  bin_finalize<<<NBINS,256,0,stream>>>(eeid, er16, bof2, bcnt, offs, buck);
  for (int c = 0; c < NCH; c++){
    int rlo = c * RPC;
    pass1_w<<<CHMAX/64, 256, 0, stream>>>(buck, offs, radial_emb, edge_sh, senders,
                                          wbuf, wpA, wpB, ybf, snd16, rlo, flag);
    pass2_reduce<<<RPC/2, 256, 0, stream>>>(offs, sv16, wpA, wpB, ybf, snd16,
                                            accb, rlo);
    pass2_epilogue<<<(RPC+15)/16, 256, 0, stream>>>(accb, wbuf, node_scalars,
                                                    node_vectors, species,
                                                    d_out, rlo, flag);
  }
}

// Round 14
// 371.379 us; speedup vs baseline: 1.2636x; 1.0007x over previous
//
#include <hip/hip_runtime.h>
#include <hip/hip_bf16.h>

typedef unsigned short u16;
typedef unsigned int   u32;
typedef _Float16 h2 __attribute__((ext_vector_type(2)));
typedef short s8v __attribute__((ext_vector_type(8)));
typedef float f4v __attribute__((ext_vector_type(4)));
typedef u16 u16x4 __attribute__((ext_vector_type(4)));

#define N_NODES 50000
#define N_EDGES 800000
#define NCH   2
#define RPC   25000      // receivers per chunk
#define CHMAX 409600     // max edges per chunk (mean 400k, +21 sigma)

// binned bucket construction
#define RPB   250        // receivers per bin (chunk boundary 25000 = bin 100, aligned)
#define NBINS 200
#define EPB   4096       // edges per block in binning kernels
#define NBB   ((N_EDGES+EPB-1)/EPB)   // 196

// ---- ws layout (u32 units), total ~30.2M u32 = 120.6 MB ----
#define WB_W1H  0        // [64][4] u32 half2 (fp16 pairs of W1 columns)
#define WB_B1   256      // [64] f32
#define WB_W2F  320      // 5120 bf16 = 2560 u32, MFMA B-frag layout
#define WB_WINS 2880
#define WB_WINV 3136
#define WB_WOS  3392
#define WB_WOV  4416
#define WB_SCS  5184
#define WB_SCV  7232
#define WB_FLAG 8256
#define OFF_SV16 8260    // [50000][16][4] u16 (xs,x0,x1,x2)
#define IDX_BCNT 1608260 // 200 ints
#define IDX_BOF2 1608516 // 200 ints
#define IDX_BCUR 1608772 // 200 ints
#define IDX_OFFS 1658260 // 50001 ints
#define IDX_BUCK 1758262 // 800,000 int
#define IDX_EEID 2558264 // 800,000 u32 (bin-grouped edge ids)
#define OFF_ER16 3358264 // 800,000 u16 (bin-grouped receivers)
#define OFF_EY   3758264 // 800,000 x 2 u32 (bin-grouped edge_sh bf16 payload)
#define OFF_ESN  5358264 // 800,000 u16 (bin-grouped senders)
#define OFF_YB   5758264 // [N_EDGES] f4v (Y f32, global rank order)
#define OFF_SND  8958264 // [N_EDGES] u16 (sender, global rank order)
#define OFF_WPA  9358264 // [CHMAX][16] u16x4 (w0..w3) = 13,107,200 u32
#define OFF_WPB  22465464 // [CHMAX][16] u16 (w4) = 3,276,800 u32
#define ACC_OFF  25742264 // 25,000 x 176 f32 per-chunk accumulators

__device__ __forceinline__ float bf2f(u16 v){
  union { u32 u; float f; } x; x.u = ((u32)v) << 16; return x.f;
}
__device__ __forceinline__ u16 f2bf(float f){
  u32 u = __float_as_uint(f);
  u32 lsb = (u >> 16) & 1u;
  u32 r = u + 0x7fffu + lsb;
  return (u16)(r >> 16);
}
__device__ __forceinline__ float ldx(const void* p, long long i, int isf){
  return isf ? ((const float*)p)[i] : bf2f(((const u16*)p)[i]);
}
__device__ __forceinline__ u32 pkh2(float a, float b){
  union { u32 u; h2 v; } x; x.v.x = (_Float16)a; x.v.y = (_Float16)b; return x.u;
}
__device__ __forceinline__ float dot2(h2 a, u32 w, float c){
  union { u32 u; h2 v; } x; x.u = w;
#if __has_builtin(__builtin_amdgcn_fdot2)
  return __builtin_amdgcn_fdot2(a, x.v, c, false);
#else
  return c + (float)a.x*(float)x.v.x + (float)a.y*(float)x.v.y;
#endif
}
__device__ __forceinline__ float sigmoidf_(float x){ return 1.f/(1.f + __expf(-x)); }

__global__ void detect_dtype(const u32* __restrict__ remb_raw, int* __restrict__ flag){
  int t = threadIdx.x;           // 64 lanes, one word each
  u32 w = remb_raw[t];
  u32 lo = w & 0xffffu, hi = w >> 16;
  int okl = ((lo & 0x8000u) == 0) && (((lo >> 7) & 0xffu) <= 126u);
  int okh = ((hi & 0x8000u) == 0) && (((hi >> 7) & 0xffu) <= 126u);
  unsigned long long bad = __ballot(!(okl && okh));
  if (t == 0) *flag = (bad != 0ull) ? 1 : 0;
}

__global__ void prep_weights(const void* __restrict__ w1, const void* __restrict__ b1g,
                             const void* __restrict__ w2, const void* __restrict__ wins,
                             const void* __restrict__ winv, const void* __restrict__ wos,
                             const void* __restrict__ wov, const void* __restrict__ scs,
                             const void* __restrict__ scv, float* __restrict__ wbuf,
                             const int* __restrict__ flag){
  int t = threadIdx.x;
  int isf = *flag;
  u32* w1h  = (u32*)(wbuf + WB_W1H);
  u16* w2f  = (u16*)(wbuf + WB_W2F);
  for (int idx=t; idx<256;  idx+=256){
    int j = idx>>2, ip = idx&3;
    w1h[idx] = pkh2(ldx(w1, (2*ip)*64+j, isf), ldx(w1, (2*ip+1)*64+j, isf));
  }
  for (int idx=t; idx<64;   idx+=256){ wbuf[WB_B1+idx]  = ldx(b1g, idx, isf); }
  // MFMA B-frag layout for 16x16x32 bf16: lane holds B[k=(lane>>4)*8+j][n=lane&15]
  for (int idx=t; idx<5120; idx+=256){
    int tt = idx >> 10;           // N-tile 0..4
    int rem = idx & 1023;
    int kh = rem >> 9;            // K-half 0..1
    int rem2 = rem & 511;
    int ln = rem2 >> 3, j = rem2 & 7;
    int k = kh*32 + (ln>>4)*8 + j;
    int o = tt*16 + (ln&15);
    w2f[idx] = f2bf(ldx(w2, (long long)k*80 + o, isf));
  }
  for (int idx=t; idx<256;  idx+=256){ wbuf[WB_WINS+idx] = ldx(wins, idx, isf); }
  for (int idx=t; idx<256;  idx+=256){ wbuf[WB_WINV+idx] = ldx(winv, idx, isf); }
  for (int idx=t; idx<1024; idx+=256){ wbuf[WB_WOS+idx]  = ldx(wos, idx, isf); }
  for (int idx=t; idx<768;  idx+=256){ wbuf[WB_WOV+idx]  = ldx(wov, idx, isf); }
  for (int idx=t; idx<2048; idx+=256){ wbuf[WB_SCS+idx]  = ldx(scs, idx, isf); }
  for (int idx=t; idx<1024; idx+=256){ wbuf[WB_SCV+idx]  = ldx(scv, idx, isf); }
}

// node_pre v2: 256 threads / 16 nodes per block, 16 threads per node.
__global__ void __launch_bounds__(256) node_pre(
    const void* __restrict__ ns_g, const void* __restrict__ nv_g,
    const float* __restrict__ wbuf, u16* __restrict__ sv16,
    const int* __restrict__ flag){
  __shared__ float A[16][16];     // [node][u] scalars
  __shared__ float B[16][48];     // [node][u*3+c] vectors
  __shared__ float wsl[256], wvl[256];
  int tid = threadIdx.x;
  int isf = *flag;
  int n0 = blockIdx.x*16;         // 3125*16 = 50000 exact
  for (int i=tid;i<256;i+=256){ wsl[i]=wbuf[WB_WINS+i]; wvl[i]=wbuf[WB_WINV+i]; }
  for (int i=tid;i<256;i+=256) A[i>>4][i&15] = ldx(ns_g,(long long)n0*16+i,isf);
  for (int i=tid;i<768;i+=256) B[i/48][i%48] = ldx(nv_g,(long long)n0*48+i,isf);
  __syncthreads();
  int g = tid>>4, u = tid&15;
  float s=0.f, v0=0.f, v1=0.f, v2=0.f;
  #pragma unroll
  for (int j=0;j<16;j++){
    s  += A[g][j]*wsl[j*16+u];
    float wv = wvl[j*16+u];
    v0 += B[g][j*3+0]*wv;
    v1 += B[g][j*3+1]*wv;
    v2 += B[g][j*3+2]*wv;
  }
  u16x4 pk;
  pk[0]=f2bf(s); pk[1]=f2bf(v0); pk[2]=f2bf(v1); pk[3]=f2bf(v2);
  ((u16x4*)sv16)[(size_t)(n0+g)*16 + u] = pk;
}

// ---- binned bucket construction ----
__global__ void __launch_bounds__(256) bin_count(const int* __restrict__ receivers,
                                                 int* __restrict__ bcnt){
  __shared__ int lcnt[NBINS];
  int t = threadIdx.x;
  for (int i=t;i<NBINS;i+=256) lcnt[i]=0;
  __syncthreads();
  int base = blockIdx.x*EPB;
  for (int i=t;i<EPB;i+=256){
    int e = base+i;
    if (e<N_EDGES) atomicAdd(&lcnt[receivers[e]/RPB],1);
  }
  __syncthreads();
  for (int i=t;i<NBINS;i+=256) if (lcnt[i]) atomicAdd(&bcnt[i], lcnt[i]);
}

__global__ void bin_scan(const int* __restrict__ bcnt, int* __restrict__ binoff,
                         int* __restrict__ bincur, int* __restrict__ offs){
  __shared__ int lds[NBINS];
  int t=threadIdx.x;
  if (t<NBINS) lds[t]=bcnt[t];
  __syncthreads();
  for (int off=1; off<NBINS; off<<=1){
    int v = (t<NBINS && t>=off)? lds[t-off] : 0;
    __syncthreads();
    if (t<NBINS) lds[t]+=v;
    __syncthreads();
  }
  if (t<NBINS){ int ex = lds[t]-bcnt[t]; binoff[t]=ex; bincur[t]=ex; }
  if (t==0) offs[N_NODES] = N_EDGES;
}

// bin_scatter v2: also carries edge_sh(bf16)+sender payload through the sort
// (bf16 mode only; reads are coalesced in original edge order).
__global__ void __launch_bounds__(256) bin_scatter(const int* __restrict__ receivers,
                 const void* __restrict__ edge_sh, const int* __restrict__ senders,
                 int* __restrict__ bincur, u32* __restrict__ eeid, u16* __restrict__ er,
                 u32* __restrict__ ey, u16* __restrict__ esn,
                 const int* __restrict__ flag){
  __shared__ int lcnt[NBINS], loff[NBINS], lcur[NBINS], gbase[NBINS];
  __shared__ u32 seid[EPB];
  __shared__ u16 sr[EPB];
  __shared__ u32 sy0[EPB], sy1[EPB];
  __shared__ u16 ssn[EPB];
  int t = threadIdx.x;
  int isf = *flag;
  for (int i=t;i<NBINS;i+=256) lcnt[i]=0;
  __syncthreads();
  int base = blockIdx.x*EPB;
  int r_[16];
  #pragma unroll
  for (int k=0;k<16;k++){
    int e = base + t + k*256;
    r_[k] = (e<N_EDGES)? receivers[e] : -1;
    if (r_[k]>=0) atomicAdd(&lcnt[r_[k]/RPB],1);
  }
  __syncthreads();
  if (t<NBINS) loff[t]=lcnt[t];
  __syncthreads();
  for (int off=1; off<NBINS; off<<=1){
    int v=(t<NBINS&&t>=off)?loff[t-off]:0;
    __syncthreads();
    if (t<NBINS) loff[t]+=v;
    __syncthreads();
  }
  if (t<NBINS){
    int ex=loff[t]-lcnt[t]; loff[t]=ex; lcur[t]=ex;
    gbase[t] = lcnt[t] ? atomicAdd(&bincur[t], lcnt[t]) : 0;
  }
  __syncthreads();
  #pragma unroll
  for (int k=0;k<16;k++){
    if (r_[k]>=0){
      int e = base + t + k*256;
      int b=r_[k]/RPB;
      int p=atomicAdd(&lcur[b],1);
      seid[p]=(u32)e;
      sr[p]=(u16)r_[k];
      if (!isf){
        const u32* ys = (const u32*)edge_sh + (size_t)e*2;   // coalesced
        sy0[p]=ys[0]; sy1[p]=ys[1];
        ssn[p]=(u16)senders[e];
      }
    }
  }
  __syncthreads();
  int rem = N_EDGES - base;
  int tot = rem < EPB ? rem : EPB;
  for (int i=t;i<tot;i+=256){
    int b = sr[i]/RPB;
    int dst = gbase[b] + (i - loff[b]);
    eeid[dst]=seid[i]; er[dst]=sr[i];
    if (!isf){
      ey[(size_t)dst*2]=sy0[i]; ey[(size_t)dst*2+1]=sy1[i];
      esn[dst]=ssn[i];
    }
  }
}

// bin_finalize v2: deposits payload at final global rank (ybf f32, snd16).
__global__ void __launch_bounds__(256) bin_finalize(const u32* __restrict__ eeid,
        const u16* __restrict__ er, const int* __restrict__ binoff,
        const int* __restrict__ bcnt, const u32* __restrict__ ey,
        const u16* __restrict__ esn, int* __restrict__ offs,
        int* __restrict__ bucket, float* __restrict__ ybf,
        u16* __restrict__ snd16, const int* __restrict__ flag){
  __shared__ int deg[RPB], pfx[RPB], lcur[RPB];
  int b=blockIdx.x, t=threadIdx.x;
  int isf = *flag;
  int beg=binoff[b], cnt=bcnt[b];
  for (int i=t;i<RPB;i+=256) deg[i]=0;
  __syncthreads();
  int r0=b*RPB;
  for (int i=t;i<cnt;i+=256) atomicAdd(&deg[er[beg+i]-r0],1);
  __syncthreads();
  if (t<RPB) pfx[t]=deg[t];
  __syncthreads();
  for (int off=1; off<RPB; off<<=1){
    int v=(t<RPB&&t>=off)?pfx[t-off]:0;
    __syncthreads();
    if (t<RPB) pfx[t]+=v;
    __syncthreads();
  }
  if (t<RPB){
    int ex=pfx[t]-deg[t]; pfx[t]=ex; lcur[t]=ex;
    offs[r0+t]=beg+ex;
  }
  __syncthreads();
  for (int i=t;i<cnt;i+=256){
    int rr = er[beg+i]-r0;
    int k = atomicAdd(&lcur[rr],1);
    int rank = beg + k;
    bucket[rank] = (int)eeid[beg+i];
    if (!isf){
      u32 y0=ey[(size_t)(beg+i)*2], y1=ey[(size_t)(beg+i)*2+1];
      f4v y;
      y[0]=bf2f((u16)(y0 & 0xffffu)); y[1]=bf2f((u16)(y0 >> 16));
      y[2]=bf2f((u16)(y1 & 0xffffu)); y[3]=bf2f((u16)(y1 >> 16));
      ((f4v*)ybf)[rank] = y;
      snd16[rank] = esn[beg+i];
    }
  }
}

// pass1: per chunk, compute w[80] per edge via MFMA; wave = 16 edges.
// bf16 mode: ybf/snd16 already prefilled by binning -> ONLY remb gather here.
// f32 mode: q==0 lanes fill ybf/snd16 at global rank (old path).
__global__ void __launch_bounds__(256) pass1_w(
    const int* __restrict__ bucket, const int* __restrict__ offs,
    const void* __restrict__ remb, const void* __restrict__ edge_sh,
    const int* __restrict__ senders, const float* __restrict__ wbuf,
    u16* __restrict__ wpA, u16* __restrict__ wpB,
    float* __restrict__ ybf, u16* __restrict__ snd16,
    int rlo, const int* __restrict__ flag){
  __shared__ u16 hlds[4*16*72];        // 4 waves x 16 edges x 64 h (+8 pad)
  int tid = threadIdx.x;
  int lane = tid & 63, wid = tid >> 6;
  int isf = *flag;
  int chunkBeg = offs[rlo], chunkEnd = offs[rlo + RPC];
  int r0e = chunkBeg + (blockIdx.x*4 + wid)*16;
  if (r0e >= chunkEnd) return;         // whole-wave exit; no __syncthreads in kernel
  u16* hw = hlds + wid*(16*72);
  int e = lane & 15, q = lane >> 4;

  // ---- h for edge (r0e+e), j = q*16 .. q*16+15 ----
  int er = r0e + e;
  int eid = (er < chunkEnd) ? bucket[er] : 0;
  float re[8];
  if (isf){
    f4v ra = ((const f4v*)remb)[(size_t)eid*2];
    f4v rb = ((const f4v*)remb)[(size_t)eid*2+1];
    re[0]=ra[0]; re[1]=ra[1]; re[2]=ra[2]; re[3]=ra[3];
    re[4]=rb[0]; re[5]=rb[1]; re[6]=rb[2]; re[7]=rb[3];
    if (q == 0 && er < chunkEnd){
      ((f4v*)ybf)[er] = ((const f4v*)edge_sh)[eid];
      snd16[er] = (u16)senders[eid];
    }
  } else {
    s8v r8 = ((const s8v*)remb)[eid];
    #pragma unroll
    for (int i=0;i<8;i++) re[i] = bf2f((u16)r8[i]);
  }
  h2 reh[4];
  #pragma unroll
  for (int ip=0;ip<4;ip++){ reh[ip].x=(_Float16)re[2*ip]; reh[ip].y=(_Float16)re[2*ip+1]; }
  const u32* w1h = (const u32*)(wbuf + WB_W1H);
  const float* b1 = wbuf + WB_B1;
  #pragma unroll
  for (int jj=0;jj<16;jj++){
    int j = q*16 + jj;
    float a = b1[j];
    #pragma unroll
    for (int ip=0;ip<4;ip++) a = dot2(reh[ip], w1h[j*4+ip], a);
    a = a * sigmoidf_(a);
    hw[e*72 + j] = f2bf(a);
  }
  asm volatile("s_waitcnt lgkmcnt(0)" ::: "memory");  // wave-local LDS exchange

  // ---- B-frags (W2), 10 x 16B, coalesced, held in VGPRs ----
  const u16* w2f = (const u16*)(wbuf + WB_W2F);
  s8v bfr[5][2];
  #pragma unroll
  for (int t=0;t<5;t++)
    #pragma unroll
    for (int kh=0;kh<2;kh++)
      bfr[t][kh] = *(const s8v*)(w2f + ((t*2+kh)*64 + lane)*8);

  f4v acc[5];
  #pragma unroll
  for (int t=0;t<5;t++) acc[t] = (f4v){0.f,0.f,0.f,0.f};
  #pragma unroll
  for (int kh=0;kh<2;kh++){
    // A-frag: lane holds h[m=lane&15][k=kh*32 + q*8 + j]
    s8v af = *(const s8v*)(hw + e*72 + kh*32 + q*8);
    #pragma unroll
    for (int t=0;t<5;t++)
      acc[t] = __builtin_amdgcn_mfma_f32_16x16x32_bf16(af, bfr[t][kh], acc[t], 0,0,0);
  }
  // ---- store: C layout col=lane&15 (=u), row=q*4+reg (=edge in tile) ----
  int n = lane & 15;
  #pragma unroll
  for (int r=0;r<4;r++){
    int er2 = r0e + q*4 + r;
    if (er2 < chunkEnd){
      size_t widx = (size_t)(er2 - chunkBeg);
      u16x4 pk4;
      pk4[0]=f2bf(acc[0][r]); pk4[1]=f2bf(acc[1][r]);
      pk4[2]=f2bf(acc[2][r]); pk4[3]=f2bf(acc[3][r]);
      ((u16x4*)wpA)[widx*16 + n] = pk4;
      wpB[widx*16 + n] = f2bf(acc[4][r]);
    }
  }
}

// pass2a: 8-way edge parallelism per receiver (2 waves/receiver, block = 2 receivers).
// ybf/snd16 indexed by global rank; wpA/wpB by chunk-local index.
__global__ void __launch_bounds__(256, 4) pass2_reduce(
    const int* __restrict__ offs,
    const u16* __restrict__ sv16, const u16* __restrict__ wpA,
    const u16* __restrict__ wpB, const float* __restrict__ ybf,
    const u16* __restrict__ snd16, float* __restrict__ accbuf,
    int rlo){
  __shared__ float part[4][176];
  int tid = threadIdx.x;
  int lane = tid & 63, wid = tid >> 6;
  int u = lane & 15, q = lane >> 4;
  int pr = wid >> 1;                 // receiver slot within block (0..1)
  int wsub = wid & 1;                // wave within the pair
  int r = rlo + blockIdx.x*2 + pr;   // grid = RPC/2, exact cover
  int chunkBeg = offs[rlo];
  int beg = offs[r], end = offs[r+1];
  float As0=0.f,As1=0.f;
  float Av00=0.f,Av01=0.f,Av02=0.f, Av10=0.f,Av11=0.f,Av12=0.f, Av20=0.f,Av21=0.f,Av22=0.f;
  auto body = [&](int rank){
    size_t li = (size_t)(rank - chunkBeg);
    f4v y = ((const f4v*)ybf)[rank];
    float Y0=y[0], Yv0=y[1], Yv1=y[2], Yv2=y[3];
    int snd = snd16[rank];
    u16x4 wv = ((const u16x4*)wpA)[li*16 + u];
    float w0=bf2f(wv[0]), w1=bf2f(wv[1]), w2=bf2f(wv[2]), w3=bf2f(wv[3]);
    float w4=bf2f(wpB[li*16 + u]);
    u16x4 sv = *(const u16x4*)(sv16 + ((size_t)snd*16 + u)*4);
    float xs=bf2f(sv[0]), x0=bf2f(sv[1]), x1=bf2f(sv[2]), x2=bf2f(sv[3]);
    As0 += w0*xs*Y0;
    As1 += w1*(x0*Yv0 + x1*Yv1 + x2*Yv2);
    float t1 = w2*xs;  Av00 += t1*Yv0; Av01 += t1*Yv1; Av02 += t1*Yv2;
    float t2 = w3*Y0;  Av10 += t2*x0;  Av11 += t2*x1;  Av12 += t2*x2;
    Av20 += w4*(x1*Yv2 - x2*Yv1);
    Av21 += w4*(x2*Yv0 - x0*Yv2);
    Av22 += w4*(x0*Yv1 - x1*Yv0);
  };
  int rank = beg + wsub*4 + q;
  for (; rank + 8 < end; rank += 16){ body(rank); body(rank+8); }
  if (rank < end) body(rank);
  // butterfly reduce across q (lane xor 16, 32) -> per-wave sums on all lanes
  #define RED2(x) { x += __shfl_xor(x,16); x += __shfl_xor(x,32); }
  RED2(As0) RED2(As1)
  RED2(Av00) RED2(Av01) RED2(Av02)
  RED2(Av10) RED2(Av11) RED2(Av12)
  RED2(Av20) RED2(Av21) RED2(Av22)
  #undef RED2
  // layout: [0,16)=As0  [16,32)=As1  32 + c*48 + p*16 + u = Av[p][c]
  if (q == 0){
    float* pp = part[wid];
    pp[u]=As0;      pp[16+u]=As1;
    pp[32+u]=Av00;  pp[48+u]=Av10;  pp[64+u]=Av20;
    pp[80+u]=Av01;  pp[96+u]=Av11;  pp[112+u]=Av21;
    pp[128+u]=Av02; pp[144+u]=Av12; pp[160+u]=Av22;
  }
  __syncthreads();
  for (int i = tid; i < 352; i += 256){
    int pr2 = i / 176, idx = i - pr2*176;
    int rr = blockIdx.x*2 + pr2;
    accbuf[(size_t)rr*176 + idx] = part[pr2*2][idx] + part[pr2*2+1][idx];
  }
}

// pass2b: dense per-node epilogue, 16 threads per node, LDS-staged accumulators.
__global__ void __launch_bounds__(256) pass2_epilogue(
    const float* __restrict__ accbuf, const float* __restrict__ wbuf,
    const void* __restrict__ ns_g, const void* __restrict__ nv_g,
    const int* __restrict__ species, void* __restrict__ out,
    int rlo, const int* __restrict__ flag){
  __shared__ float sb[16*176 + 16*16 + 16*48];   // bins | ns | vin
  int tid = threadIdx.x;
  int isf = *flag;
  int n0 = rlo + blockIdx.x*16;
  int rem = rlo + RPC - n0;
  int nblk = rem < 16 ? rem : 16;
  {
    int tot = nblk*176;
    const float* src = accbuf + (size_t)(n0 - rlo)*176;
    for (int i=tid; i<tot; i+=256) sb[i] = src[i];
    float* nsb = sb + 2816;
    for (int i=tid; i<nblk*16; i+=256)
      nsb[i] = ldx(ns_g, (long long)n0*16 + i, isf);
    float* vinb = sb + 2816 + 256;
    for (int i=tid; i<nblk*48; i+=256)
      vinb[i] = ldx(nv_g, (long long)n0*48 + i, isf);
  }
  __syncthreads();
  int g = tid >> 4, u = tid & 15;
  if (g >= nblk) return;
  int nn = n0 + g;
  const float* bin  = sb + g*176;
  const float* nsb  = sb + 2816 + g*16;
  const float* vinb = sb + 2816 + 256 + g*48;
  int sp = species[nn];
  const float* wos = wbuf + WB_WOS;
  const float* scs = wbuf + WB_SCS + sp*512;
  const float* wov = wbuf + WB_WOV;
  const float* scv = wbuf + WB_SCV + sp*256;
  float p0 = 0.f, p1 = 0.f;
  #pragma unroll
  for (int j=0;j<32;j++){
    float a = bin[j]*0.25f;
    p0 += a*wos[j*32+u];
    p1 += a*wos[j*32+16+u];
  }
  #pragma unroll
  for (int j=0;j<16;j++){
    float nu = nsb[j];
    p0 += nu*scs[j*32+u];
    p1 += nu*scs[j*32+16+u];
  }
  float gate = sigmoidf_(p1);
  float os = p0*sigmoidf_(p0) + nsb[u];
  float pv0, pv1, pv2;
  {
    float a0=0.f, a1=0.f, a2=0.f;
    #pragma unroll
    for (int j=0;j<48;j++){
      float wv = wov[j*16+u];
      a0 += bin[32 + 0*48 + j]*0.25f*wv;
      a1 += bin[32 + 1*48 + j]*0.25f*wv;
      a2 += bin[32 + 2*48 + j]*0.25f*wv;
    }
    #pragma unroll
    for (int j=0;j<16;j++){
      float sv = scv[j*16+u];
      a0 += vinb[j*3+0]*sv;
      a1 += vinb[j*3+1]*sv;
      a2 += vinb[j*3+2]*sv;
    }
    pv0 = a0*gate + vinb[u*3+0];
    pv1 = a1*gate + vinb[u*3+1];
    pv2 = a2*gate + vinb[u*3+2];
  }
  if (isf){
    float* orow = (float*)out + (size_t)nn*64;
    orow[u] = os;
    orow[16 + u*3 + 0] = pv0;
    orow[16 + u*3 + 1] = pv1;
    orow[16 + u*3 + 2] = pv2;
  } else {
    u16* orow = (u16*)out + (size_t)nn*64;
    orow[u] = f2bf(os);
    orow[16 + u*3 + 0] = f2bf(pv0);
    orow[16 + u*3 + 1] = f2bf(pv1);
    orow[16 + u*3 + 2] = f2bf(pv2);
  }
}

extern "C" void kernel_launch(void* const* d_in, const int* in_sizes, int n_in,
                              void* d_out, int out_size, void* d_ws, size_t ws_size,
                              hipStream_t stream){
  const void* node_scalars = d_in[0];
  const void* node_vectors = d_in[1];
  const void* edge_sh      = d_in[2];
  const void* radial_emb   = d_in[3];
  const int* senders      = (const int*)d_in[4];
  const int* receivers    = (const int*)d_in[5];
  const int* species      = (const int*)d_in[6];
  const void* W_in_s  = d_in[7];
  const void* W_in_v  = d_in[8];
  const void* mlp_w1  = d_in[9];
  const void* mlp_b1  = d_in[10];
  const void* mlp_w2  = d_in[11];
  const void* W_out_s = d_in[12];
  const void* W_out_v = d_in[13];
  const void* sc_s    = d_in[14];
  const void* sc_v    = d_in[15];

  float* wsf  = (float*)d_ws;
  int*   wsi  = (int*)d_ws;
  u32*   wsu  = (u32*)d_ws;
  float* wbuf = wsf;
  u16*   sv16 = (u16*)(wsu + OFF_SV16);
  int*   bcnt = wsi + IDX_BCNT;
  int*   bof2 = wsi + IDX_BOF2;
  int*   bcur = wsi + IDX_BCUR;
  int*   offs = wsi + IDX_OFFS;
  int*   buck = wsi + IDX_BUCK;
  u32*   eeid = wsu + IDX_EEID;
  u16*   er16 = (u16*)(wsu + OFF_ER16);
  u32*   ey   = wsu + OFF_EY;
  u16*   esn  = (u16*)(wsu + OFF_ESN);
  float* ybf  = wsf + OFF_YB;
  u16*   snd16= (u16*)(wsu + OFF_SND);
  u16*   wpA  = (u16*)(wsu + OFF_WPA);
  u16*   wpB  = (u16*)(wsu + OFF_WPB);
  float* accb = wsf + ACC_OFF;
  int*   flag = (int*)(wbuf + WB_FLAG);

  detect_dtype<<<1,64,0,stream>>>((const u32*)radial_emb, flag);
  hipMemsetAsync(bcnt, 0, NBINS*sizeof(int), stream);
  prep_weights<<<1,256,0,stream>>>(mlp_w1, mlp_b1, mlp_w2, W_in_s, W_in_v,
                                   W_out_s, W_out_v, sc_s, sc_v, wbuf, flag);
  node_pre<<<N_NODES/16,256,0,stream>>>(node_scalars, node_vectors, wbuf,
                                        sv16, flag);
  bin_count<<<NBB,256,0,stream>>>(receivers, bcnt);
  bin_scan<<<1,256,0,stream>>>(bcnt, bof2, bcur, offs);
  bin_scatter<<<NBB,256,0,stream>>>(receivers, edge_sh, senders, bcur,
                                    eeid, er16, ey, esn, flag);
  bin_finalize<<<NBINS,256,0,stream>>>(eeid, er16, bof2, bcnt, ey, esn,
                                       offs, buck, ybf, snd16, flag);
  for (int c = 0; c < NCH; c++){
    int rlo = c * RPC;
    pass1_w<<<CHMAX/64, 256, 0, stream>>>(buck, offs, radial_emb, edge_sh, senders,
                                          wbuf, wpA, wpB, ybf, snd16, rlo, flag);
    pass2_reduce<<<RPC/2, 256, 0, stream>>>(offs, sv16, wpA, wpB, ybf, snd16,
                                            accb, rlo);
    pass2_epilogue<<<(RPC+15)/16, 256, 0, stream>>>(accb, wbuf, node_scalars,
                                                    node_vectors, species,
                                                    d_out, rlo, flag);
  }
}

// Round 15
// 368.725 us; speedup vs baseline: 1.2727x; 1.0072x over previous
//
#include <hip/hip_runtime.h>
#include <hip/hip_bf16.h>

typedef unsigned short u16;
typedef unsigned int   u32;
typedef _Float16 h2 __attribute__((ext_vector_type(2)));
typedef short s8v __attribute__((ext_vector_type(8)));
typedef float f4v __attribute__((ext_vector_type(4)));
typedef u16 u16x4 __attribute__((ext_vector_type(4)));

#define N_NODES 50000
#define N_EDGES 800000

// binned bucket construction
#define RPB   250        // receivers per bin
#define NBINS 200
#define EPB   4096       // edges per block in binning kernels
#define NBB   ((N_EDGES+EPB-1)/EPB)   // 196

// ---- ws layout (u32 units), total ~50.1M u32 = 200 MB ----
#define WB_W1H  0        // [64][4] u32 half2 (fp16 pairs of W1 columns)
#define WB_B1   256      // [64] f32
#define WB_W2F  320      // 5120 bf16 = 2560 u32, MFMA B-frag layout
#define WB_WINS 2880
#define WB_WINV 3136
#define WB_WOS  3392
#define WB_WOV  4416
#define WB_SCS  5184
#define WB_SCV  7232
#define WB_FLAG 8256
#define OFF_SV16 8260    // [50000][16][4] u16 (xs,x0,x1,x2)
#define IDX_BCNT 1608260 // 200 ints
#define IDX_BOF2 1608460 // 200 ints
#define IDX_BCUR 1608660 // 200 ints
#define IDX_OFFS 1608960 // 50001 ints
#define IDX_BUCK 1659000 // 800,000 int
#define IDX_EEID 2459000 // 800,000 u32 (bin-grouped edge ids)
#define OFF_ER16 3259000 // 800,000 u16 (bin-grouped receivers)
#define OFF_EY   3659000 // 800,000 x 2 u32 (bin-grouped edge_sh bf16 payload)
#define OFF_ESN  5259000 // 800,000 u16 (bin-grouped senders)
#define OFF_YB   5659000 // [N_EDGES] f4v (Y f32, global rank order)
#define OFF_SND  8859000 // [N_EDGES] u16 (sender, global rank order)
#define OFF_WPA  9259000 // [N_EDGES][16] u16x4 (w0..w3) = 25,600,000 u32
#define OFF_WPB  34859000 // [N_EDGES][16] u16 (w4) = 6,400,000 u32
#define ACC_OFF  41259000 // 50,000 x 176 f32 accumulators

__device__ __forceinline__ float bf2f(u16 v){
  union { u32 u; float f; } x; x.u = ((u32)v) << 16; return x.f;
}
__device__ __forceinline__ u16 f2bf(float f){
  u32 u = __float_as_uint(f);
  u32 lsb = (u >> 16) & 1u;
  u32 r = u + 0x7fffu + lsb;
  return (u16)(r >> 16);
}
__device__ __forceinline__ float ldx(const void* p, long long i, int isf){
  return isf ? ((const float*)p)[i] : bf2f(((const u16*)p)[i]);
}
__device__ __forceinline__ u32 pkh2(float a, float b){
  union { u32 u; h2 v; } x; x.v.x = (_Float16)a; x.v.y = (_Float16)b; return x.u;
}
__device__ __forceinline__ float dot2(h2 a, u32 w, float c){
  union { u32 u; h2 v; } x; x.u = w;
#if __has_builtin(__builtin_amdgcn_fdot2)
  return __builtin_amdgcn_fdot2(a, x.v, c, false);
#else
  return c + (float)a.x*(float)x.v.x + (float)a.y*(float)x.v.y;
#endif
}
__device__ __forceinline__ float sigmoidf_(float x){ return 1.f/(1.f + __expf(-x)); }

__global__ void detect_dtype(const u32* __restrict__ remb_raw, int* __restrict__ flag){
  int t = threadIdx.x;           // 64 lanes, one word each
  u32 w = remb_raw[t];
  u32 lo = w & 0xffffu, hi = w >> 16;
  int okl = ((lo & 0x8000u) == 0) && (((lo >> 7) & 0xffu) <= 126u);
  int okh = ((hi & 0x8000u) == 0) && (((hi >> 7) & 0xffu) <= 126u);
  unsigned long long bad = __ballot(!(okl && okh));
  if (t == 0) *flag = (bad != 0ull) ? 1 : 0;
}

__global__ void prep_weights(const void* __restrict__ w1, const void* __restrict__ b1g,
                             const void* __restrict__ w2, const void* __restrict__ wins,
                             const void* __restrict__ winv, const void* __restrict__ wos,
                             const void* __restrict__ wov, const void* __restrict__ scs,
                             const void* __restrict__ scv, float* __restrict__ wbuf,
                             const int* __restrict__ flag){
  int t = threadIdx.x;
  int isf = *flag;
  u32* w1h  = (u32*)(wbuf + WB_W1H);
  u16* w2f  = (u16*)(wbuf + WB_W2F);
  for (int idx=t; idx<256;  idx+=256){
    int j = idx>>2, ip = idx&3;
    w1h[idx] = pkh2(ldx(w1, (2*ip)*64+j, isf), ldx(w1, (2*ip+1)*64+j, isf));
  }
  for (int idx=t; idx<64;   idx+=256){ wbuf[WB_B1+idx]  = ldx(b1g, idx, isf); }
  // MFMA B-frag layout for 16x16x32 bf16: lane holds B[k=(lane>>4)*8+j][n=lane&15]
  for (int idx=t; idx<5120; idx+=256){
    int tt = idx >> 10;           // N-tile 0..4
    int rem = idx & 1023;
    int kh = rem >> 9;            // K-half 0..1
    int rem2 = rem & 511;
    int ln = rem2 >> 3, j = rem2 & 7;
    int k = kh*32 + (ln>>4)*8 + j;
    int o = tt*16 + (ln&15);
    w2f[idx] = f2bf(ldx(w2, (long long)k*80 + o, isf));
  }
  for (int idx=t; idx<256;  idx+=256){ wbuf[WB_WINS+idx] = ldx(wins, idx, isf); }
  for (int idx=t; idx<256;  idx+=256){ wbuf[WB_WINV+idx] = ldx(winv, idx, isf); }
  for (int idx=t; idx<1024; idx+=256){ wbuf[WB_WOS+idx]  = ldx(wos, idx, isf); }
  for (int idx=t; idx<768;  idx+=256){ wbuf[WB_WOV+idx]  = ldx(wov, idx, isf); }
  for (int idx=t; idx<2048; idx+=256){ wbuf[WB_SCS+idx]  = ldx(scs, idx, isf); }
  for (int idx=t; idx<1024; idx+=256){ wbuf[WB_SCV+idx]  = ldx(scv, idx, isf); }
}

// node_pre v2: 256 threads / 16 nodes per block, 16 threads per node.
__global__ void __launch_bounds__(256) node_pre(
    const void* __restrict__ ns_g, const void* __restrict__ nv_g,
    const float* __restrict__ wbuf, u16* __restrict__ sv16,
    const int* __restrict__ flag){
  __shared__ float A[16][16];     // [node][u] scalars
  __shared__ float B[16][48];     // [node][u*3+c] vectors
  __shared__ float wsl[256], wvl[256];
  int tid = threadIdx.x;
  int isf = *flag;
  int n0 = blockIdx.x*16;         // 3125*16 = 50000 exact
  for (int i=tid;i<256;i+=256){ wsl[i]=wbuf[WB_WINS+i]; wvl[i]=wbuf[WB_WINV+i]; }
  for (int i=tid;i<256;i+=256) A[i>>4][i&15] = ldx(ns_g,(long long)n0*16+i,isf);
  for (int i=tid;i<768;i+=256) B[i/48][i%48] = ldx(nv_g,(long long)n0*48+i,isf);
  __syncthreads();
  int g = tid>>4, u = tid&15;
  float s=0.f, v0=0.f, v1=0.f, v2=0.f;
  #pragma unroll
  for (int j=0;j<16;j++){
    s  += A[g][j]*wsl[j*16+u];
    float wv = wvl[j*16+u];
    v0 += B[g][j*3+0]*wv;
    v1 += B[g][j*3+1]*wv;
    v2 += B[g][j*3+2]*wv;
  }
  u16x4 pk;
  pk[0]=f2bf(s); pk[1]=f2bf(v0); pk[2]=f2bf(v1); pk[3]=f2bf(v2);
  ((u16x4*)sv16)[(size_t)(n0+g)*16 + u] = pk;
}

// ---- binned bucket construction ----
__global__ void __launch_bounds__(256) bin_count(const int* __restrict__ receivers,
                                                 int* __restrict__ bcnt){
  __shared__ int lcnt[NBINS];
  int t = threadIdx.x;
  for (int i=t;i<NBINS;i+=256) lcnt[i]=0;
  __syncthreads();
  int base = blockIdx.x*EPB;
  for (int i=t;i<EPB;i+=256){
    int e = base+i;
    if (e<N_EDGES) atomicAdd(&lcnt[receivers[e]/RPB],1);
  }
  __syncthreads();
  for (int i=t;i<NBINS;i+=256) if (lcnt[i]) atomicAdd(&bcnt[i], lcnt[i]);
}

__global__ void bin_scan(const int* __restrict__ bcnt, int* __restrict__ binoff,
                         int* __restrict__ bincur, int* __restrict__ offs){
  __shared__ int lds[NBINS];
  int t=threadIdx.x;
  if (t<NBINS) lds[t]=bcnt[t];
  __syncthreads();
  for (int off=1; off<NBINS; off<<=1){
    int v = (t<NBINS && t>=off)? lds[t-off] : 0;
    __syncthreads();
    if (t<NBINS) lds[t]+=v;
    __syncthreads();
  }
  if (t<NBINS){ int ex = lds[t]-bcnt[t]; binoff[t]=ex; bincur[t]=ex; }
  if (t==0) offs[N_NODES] = N_EDGES;
}

// bin_scatter v2: also carries edge_sh(bf16)+sender payload through the sort.
__global__ void __launch_bounds__(256) bin_scatter(const int* __restrict__ receivers,
                 const void* __restrict__ edge_sh, const int* __restrict__ senders,
                 int* __restrict__ bincur, u32* __restrict__ eeid, u16* __restrict__ er,
                 u32* __restrict__ ey, u16* __restrict__ esn,
                 const int* __restrict__ flag){
  __shared__ int lcnt[NBINS], loff[NBINS], lcur[NBINS], gbase[NBINS];
  __shared__ u32 seid[EPB];
  __shared__ u16 sr[EPB];
  __shared__ u32 sy0[EPB], sy1[EPB];
  __shared__ u16 ssn[EPB];
  int t = threadIdx.x;
  int isf = *flag;
  for (int i=t;i<NBINS;i+=256) lcnt[i]=0;
  __syncthreads();
  int base = blockIdx.x*EPB;
  int r_[16];
  #pragma unroll
  for (int k=0;k<16;k++){
    int e = base + t + k*256;
    r_[k] = (e<N_EDGES)? receivers[e] : -1;
    if (r_[k]>=0) atomicAdd(&lcnt[r_[k]/RPB],1);
  }
  __syncthreads();
  if (t<NBINS) loff[t]=lcnt[t];
  __syncthreads();
  for (int off=1; off<NBINS; off<<=1){
    int v=(t<NBINS&&t>=off)?loff[t-off]:0;
    __syncthreads();
    if (t<NBINS) loff[t]+=v;
    __syncthreads();
  }
  if (t<NBINS){
    int ex=loff[t]-lcnt[t]; loff[t]=ex; lcur[t]=ex;
    gbase[t] = lcnt[t] ? atomicAdd(&bincur[t], lcnt[t]) : 0;
  }
  __syncthreads();
  #pragma unroll
  for (int k=0;k<16;k++){
    if (r_[k]>=0){
      int e = base + t + k*256;
      int b=r_[k]/RPB;
      int p=atomicAdd(&lcur[b],1);
      seid[p]=(u32)e;
      sr[p]=(u16)r_[k];
      if (!isf){
        const u32* ys = (const u32*)edge_sh + (size_t)e*2;   // coalesced
        sy0[p]=ys[0]; sy1[p]=ys[1];
        ssn[p]=(u16)senders[e];
      }
    }
  }
  __syncthreads();
  int rem = N_EDGES - base;
  int tot = rem < EPB ? rem : EPB;
  for (int i=t;i<tot;i+=256){
    int b = sr[i]/RPB;
    int dst = gbase[b] + (i - loff[b]);
    eeid[dst]=seid[i]; er[dst]=sr[i];
    if (!isf){
      ey[(size_t)dst*2]=sy0[i]; ey[(size_t)dst*2+1]=sy1[i];
      esn[dst]=ssn[i];
    }
  }
}

// bin_finalize v2: deposits payload at final global rank (ybf f32, snd16).
__global__ void __launch_bounds__(256) bin_finalize(const u32* __restrict__ eeid,
        const u16* __restrict__ er, const int* __restrict__ binoff,
        const int* __restrict__ bcnt, const u32* __restrict__ ey,
        const u16* __restrict__ esn, int* __restrict__ offs,
        int* __restrict__ bucket, float* __restrict__ ybf,
        u16* __restrict__ snd16, const int* __restrict__ flag){
  __shared__ int deg[RPB], pfx[RPB], lcur[RPB];
  int b=blockIdx.x, t=threadIdx.x;
  int isf = *flag;
  int beg=binoff[b], cnt=bcnt[b];
  for (int i=t;i<RPB;i+=256) deg[i]=0;
  __syncthreads();
  int r0=b*RPB;
  for (int i=t;i<cnt;i+=256) atomicAdd(&deg[er[beg+i]-r0],1);
  __syncthreads();
  if (t<RPB) pfx[t]=deg[t];
  __syncthreads();
  for (int off=1; off<RPB; off<<=1){
    int v=(t<RPB&&t>=off)?pfx[t-off]:0;
    __syncthreads();
    if (t<RPB) pfx[t]+=v;
    __syncthreads();
  }
  if (t<RPB){
    int ex=pfx[t]-deg[t]; pfx[t]=ex; lcur[t]=ex;
    offs[r0+t]=beg+ex;
  }
  __syncthreads();
  for (int i=t;i<cnt;i+=256){
    int rr = er[beg+i]-r0;
    int k = atomicAdd(&lcur[rr],1);
    int rank = beg + k;
    bucket[rank] = (int)eeid[beg+i];
    if (!isf){
      u32 y0=ey[(size_t)(beg+i)*2], y1=ey[(size_t)(beg+i)*2+1];
      f4v y;
      y[0]=bf2f((u16)(y0 & 0xffffu)); y[1]=bf2f((u16)(y0 >> 16));
      y[2]=bf2f((u16)(y1 & 0xffffu)); y[3]=bf2f((u16)(y1 >> 16));
      ((f4v*)ybf)[rank] = y;
      snd16[rank] = esn[beg+i];
    }
  }
}

// pass1: single launch over all edges; wave = 16 edges (50000 tiles exact).
// bf16 mode: ybf/snd16 prefilled by binning -> ONLY remb gather here.
// f32 mode: q==0 lanes fill ybf/snd16 at global rank.
__global__ void __launch_bounds__(256) pass1_w(
    const int* __restrict__ bucket,
    const void* __restrict__ remb, const void* __restrict__ edge_sh,
    const int* __restrict__ senders, const float* __restrict__ wbuf,
    u16* __restrict__ wpA, u16* __restrict__ wpB,
    float* __restrict__ ybf, u16* __restrict__ snd16,
    const int* __restrict__ flag){
  __shared__ u16 hlds[4*16*72];        // 4 waves x 16 edges x 64 h (+8 pad)
  int tid = threadIdx.x;
  int lane = tid & 63, wid = tid >> 6;
  int isf = *flag;
  int r0e = (blockIdx.x*4 + wid)*16;   // 12500*4*16 = 800000 exact
  u16* hw = hlds + wid*(16*72);
  int e = lane & 15, q = lane >> 4;

  // ---- h for edge (r0e+e), j = q*16 .. q*16+15 ----
  int er = r0e + e;
  int eid = bucket[er];
  float re[8];
  if (isf){
    f4v ra = ((const f4v*)remb)[(size_t)eid*2];
    f4v rb = ((const f4v*)remb)[(size_t)eid*2+1];
    re[0]=ra[0]; re[1]=ra[1]; re[2]=ra[2]; re[3]=ra[3];
    re[4]=rb[0]; re[5]=rb[1]; re[6]=rb[2]; re[7]=rb[3];
    if (q == 0){
      ((f4v*)ybf)[er] = ((const f4v*)edge_sh)[eid];
      snd16[er] = (u16)senders[eid];
    }
  } else {
    s8v r8 = ((const s8v*)remb)[eid];
    #pragma unroll
    for (int i=0;i<8;i++) re[i] = bf2f((u16)r8[i]);
  }
  h2 reh[4];
  #pragma unroll
  for (int ip=0;ip<4;ip++){ reh[ip].x=(_Float16)re[2*ip]; reh[ip].y=(_Float16)re[2*ip+1]; }
  const u32* w1h = (const u32*)(wbuf + WB_W1H);
  const float* b1 = wbuf + WB_B1;
  #pragma unroll
  for (int jj=0;jj<16;jj++){
    int j = q*16 + jj;
    float a = b1[j];
    #pragma unroll
    for (int ip=0;ip<4;ip++) a = dot2(reh[ip], w1h[j*4+ip], a);
    a = a * sigmoidf_(a);
    hw[e*72 + j] = f2bf(a);
  }
  asm volatile("s_waitcnt lgkmcnt(0)" ::: "memory");  // wave-local LDS exchange

  // ---- B-frags (W2), 10 x 16B, coalesced, held in VGPRs ----
  const u16* w2f = (const u16*)(wbuf + WB_W2F);
  s8v bfr[5][2];
  #pragma unroll
  for (int t=0;t<5;t++)
    #pragma unroll
    for (int kh=0;kh<2;kh++)
      bfr[t][kh] = *(const s8v*)(w2f + ((t*2+kh)*64 + lane)*8);

  f4v acc[5];
  #pragma unroll
  for (int t=0;t<5;t++) acc[t] = (f4v){0.f,0.f,0.f,0.f};
  #pragma unroll
  for (int kh=0;kh<2;kh++){
    // A-frag: lane holds h[m=lane&15][k=kh*32 + q*8 + j]
    s8v af = *(const s8v*)(hw + e*72 + kh*32 + q*8);
    #pragma unroll
    for (int t=0;t<5;t++)
      acc[t] = __builtin_amdgcn_mfma_f32_16x16x32_bf16(af, bfr[t][kh], acc[t], 0,0,0);
  }
  // ---- store: C layout col=lane&15 (=u), row=q*4+reg (=edge in tile) ----
  int n = lane & 15;
  #pragma unroll
  for (int r=0;r<4;r++){
    size_t widx = (size_t)(r0e + q*4 + r);
    u16x4 pk4;
    pk4[0]=f2bf(acc[0][r]); pk4[1]=f2bf(acc[1][r]);
    pk4[2]=f2bf(acc[2][r]); pk4[3]=f2bf(acc[3][r]);
    ((u16x4*)wpA)[widx*16 + n] = pk4;
    wpB[widx*16 + n] = f2bf(acc[4][r]);
  }
}

// pass2a: 8-way edge parallelism per receiver (2 waves/receiver, block = 2 receivers).
// All per-edge inputs are global-rank streams; only sv16 is a gather (depth-1 chain).
__global__ void __launch_bounds__(256, 4) pass2_reduce(
    const int* __restrict__ offs,
    const u16* __restrict__ sv16, const u16* __restrict__ wpA,
    const u16* __restrict__ wpB, const float* __restrict__ ybf,
    const u16* __restrict__ snd16, float* __restrict__ accbuf){
  __shared__ float part[4][176];
  int tid = threadIdx.x;
  int lane = tid & 63, wid = tid >> 6;
  int u = lane & 15, q = lane >> 4;
  int pr = wid >> 1;                 // receiver slot within block (0..1)
  int wsub = wid & 1;                // wave within the pair
  int r = blockIdx.x*2 + pr;         // grid = N_NODES/2, exact cover
  int beg = offs[r], end = offs[r+1];
  float As0=0.f,As1=0.f;
  float Av00=0.f,Av01=0.f,Av02=0.f, Av10=0.f,Av11=0.f,Av12=0.f, Av20=0.f,Av21=0.f,Av22=0.f;
  auto body = [&](int rank){
    size_t li = (size_t)rank;
    f4v y = ((const f4v*)ybf)[li];
    float Y0=y[0], Yv0=y[1], Yv1=y[2], Yv2=y[3];
    int snd = snd16[li];
    u16x4 wv = ((const u16x4*)wpA)[li*16 + u];
    float w0=bf2f(wv[0]), w1=bf2f(wv[1]), w2=bf2f(wv[2]), w3=bf2f(wv[3]);
    float w4=bf2f(wpB[li*16 + u]);
    u16x4 sv = *(const u16x4*)(sv16 + ((size_t)snd*16 + u)*4);
    float xs=bf2f(sv[0]), x0=bf2f(sv[1]), x1=bf2f(sv[2]), x2=bf2f(sv[3]);
    As0 += w0*xs*Y0;
    As1 += w1*(x0*Yv0 + x1*Yv1 + x2*Yv2);
    float t1 = w2*xs;  Av00 += t1*Yv0; Av01 += t1*Yv1; Av02 += t1*Yv2;
    float t2 = w3*Y0;  Av10 += t2*x0;  Av11 += t2*x1;  Av12 += t2*x2;
    Av20 += w4*(x1*Yv2 - x2*Yv1);
    Av21 += w4*(x2*Yv0 - x0*Yv2);
    Av22 += w4*(x0*Yv1 - x1*Yv0);
  };
  int rank = beg + wsub*4 + q;
  for (; rank + 8 < end; rank += 16){ body(rank); body(rank+8); }
  if (rank < end) body(rank);
  // butterfly reduce across q (lane xor 16, 32) -> per-wave sums on all lanes
  #define RED2(x) { x += __shfl_xor(x,16); x += __shfl_xor(x,32); }
  RED2(As0) RED2(As1)
  RED2(Av00) RED2(Av01) RED2(Av02)
  RED2(Av10) RED2(Av11) RED2(Av12)
  RED2(Av20) RED2(Av21) RED2(Av22)
  #undef RED2
  // layout: [0,16)=As0  [16,32)=As1  32 + c*48 + p*16 + u = Av[p][c]
  if (q == 0){
    float* pp = part[wid];
    pp[u]=As0;      pp[16+u]=As1;
    pp[32+u]=Av00;  pp[48+u]=Av10;  pp[64+u]=Av20;
    pp[80+u]=Av01;  pp[96+u]=Av11;  pp[112+u]=Av21;
    pp[128+u]=Av02; pp[144+u]=Av12; pp[160+u]=Av22;
  }
  __syncthreads();
  for (int i = tid; i < 352; i += 256){
    int pr2 = i / 176, idx = i - pr2*176;
    int rr = blockIdx.x*2 + pr2;
    accbuf[(size_t)rr*176 + idx] = part[pr2*2][idx] + part[pr2*2+1][idx];
  }
}

// pass2b: dense per-node epilogue, 16 threads per node, LDS-staged accumulators.
__global__ void __launch_bounds__(256) pass2_epilogue(
    const float* __restrict__ accbuf, const float* __restrict__ wbuf,
    const void* __restrict__ ns_g, const void* __restrict__ nv_g,
    const int* __restrict__ species, void* __restrict__ out,
    const int* __restrict__ flag){
  __shared__ float sb[16*176 + 16*16 + 16*48];   // bins | ns | vin
  int tid = threadIdx.x;
  int isf = *flag;
  int n0 = blockIdx.x*16;             // 3125*16 = 50000 exact
  {
    const float* src = accbuf + (size_t)n0*176;
    for (int i=tid; i<16*176; i+=256) sb[i] = src[i];
    float* nsb = sb + 2816;
    for (int i=tid; i<256; i+=256)
      nsb[i] = ldx(ns_g, (long long)n0*16 + i, isf);
    float* vinb = sb + 2816 + 256;
    for (int i=tid; i<768; i+=256)
      vinb[i] = ldx(nv_g, (long long)n0*48 + i, isf);
  }
  __syncthreads();
  int g = tid >> 4, u = tid & 15;
  int nn = n0 + g;
  const float* bin  = sb + g*176;
  const float* nsb  = sb + 2816 + g*16;
  const float* vinb = sb + 2816 + 256 + g*48;
  int sp = species[nn];
  const float* wos = wbuf + WB_WOS;
  const float* scs = wbuf + WB_SCS + sp*512;
  const float* wov = wbuf + WB_WOV;
  const float* scv = wbuf + WB_SCV + sp*256;
  float p0 = 0.f, p1 = 0.f;
  #pragma unroll
  for (int j=0;j<32;j++){
    float a = bin[j]*0.25f;
    p0 += a*wos[j*32+u];
    p1 += a*wos[j*32+16+u];
  }
  #pragma unroll
  for (int j=0;j<16;j++){
    float nu = nsb[j];
    p0 += nu*scs[j*32+u];
    p1 += nu*scs[j*32+16+u];
  }
  float gate = sigmoidf_(p1);
  float os = p0*sigmoidf_(p0) + nsb[u];
  float pv0, pv1, pv2;
  {
    float a0=0.f, a1=0.f, a2=0.f;
    #pragma unroll
    for (int j=0;j<48;j++){
      float wv = wov[j*16+u];
      a0 += bin[32 + 0*48 + j]*0.25f*wv;
      a1 += bin[32 + 1*48 + j]*0.25f*wv;
      a2 += bin[32 + 2*48 + j]*0.25f*wv;
    }
    #pragma unroll
    for (int j=0;j<16;j++){
      float sv = scv[j*16+u];
      a0 += vinb[j*3+0]*sv;
      a1 += vinb[j*3+1]*sv;
      a2 += vinb[j*3+2]*sv;
    }
    pv0 = a0*gate + vinb[u*3+0];
    pv1 = a1*gate + vinb[u*3+1];
    pv2 = a2*gate + vinb[u*3+2];
  }
  if (isf){
    float* orow = (float*)out + (size_t)nn*64;
    orow[u] = os;
    orow[16 + u*3 + 0] = pv0;
    orow[16 + u*3 + 1] = pv1;
    orow[16 + u*3 + 2] = pv2;
  } else {
    u16* orow = (u16*)out + (size_t)nn*64;
    orow[u] = f2bf(os);
    orow[16 + u*3 + 0] = f2bf(pv0);
    orow[16 + u*3 + 1] = f2bf(pv1);
    orow[16 + u*3 + 2] = f2bf(pv2);
  }
}

extern "C" void kernel_launch(void* const* d_in, const int* in_sizes, int n_in,
                              void* d_out, int out_size, void* d_ws, size_t ws_size,
                              hipStream_t stream){
  const void* node_scalars = d_in[0];
  const void* node_vectors = d_in[1];
  const void* edge_sh      = d_in[2];
  const void* radial_emb   = d_in[3];
  const int* senders      = (const int*)d_in[4];
  const int* receivers    = (const int*)d_in[5];
  const int* species      = (const int*)d_in[6];
  const void* W_in_s  = d_in[7];
  const void* W_in_v  = d_in[8];
  const void* mlp_w1  = d_in[9];
  const void* mlp_b1  = d_in[10];
  const void* mlp_w2  = d_in[11];
  const void* W_out_s = d_in[12];
  const void* W_out_v = d_in[13];
  const void* sc_s    = d_in[14];
  const void* sc_v    = d_in[15];

  float* wsf  = (float*)d_ws;
  int*   wsi  = (int*)d_ws;
  u32*   wsu  = (u32*)d_ws;
  float* wbuf = wsf;
  u16*   sv16 = (u16*)(wsu + OFF_SV16);
  int*   bcnt = wsi + IDX_BCNT;
  int*   bof2 = wsi + IDX_BOF2;
  int*   bcur = wsi + IDX_BCUR;
  int*   offs = wsi + IDX_OFFS;
  int*   buck = wsi + IDX_BUCK;
  u32*   eeid = wsu + IDX_EEID;
  u16*   er16 = (u16*)(wsu + OFF_ER16);
  u32*   ey   = wsu + OFF_EY;
  u16*   esn  = (u16*)(wsu + OFF_ESN);
  float* ybf  = wsf + OFF_YB;
  u16*   snd16= (u16*)(wsu + OFF_SND);
  u16*   wpA  = (u16*)(wsu + OFF_WPA);
  u16*   wpB  = (u16*)(wsu + OFF_WPB);
  float* accb = wsf + ACC_OFF;
  int*   flag = (int*)(wbuf + WB_FLAG);

  detect_dtype<<<1,64,0,stream>>>((const u32*)radial_emb, flag);
  hipMemsetAsync(bcnt, 0, NBINS*sizeof(int), stream);
  prep_weights<<<1,256,0,stream>>>(mlp_w1, mlp_b1, mlp_w2, W_in_s, W_in_v,
                                   W_out_s, W_out_v, sc_s, sc_v, wbuf, flag);
  node_pre<<<N_NODES/16,256,0,stream>>>(node_scalars, node_vectors, wbuf,
                                        sv16, flag);
  bin_count<<<NBB,256,0,stream>>>(receivers, bcnt);
  bin_scan<<<1,256,0,stream>>>(bcnt, bof2, bcur, offs);
  bin_scatter<<<NBB,256,0,stream>>>(receivers, edge_sh, senders, bcur,
                                    eeid, er16, ey, esn, flag);
  bin_finalize<<<NBINS,256,0,stream>>>(eeid, er16, bof2, bcnt, ey, esn,
                                       offs, buck, ybf, snd16, flag);
  pass1_w<<<N_EDGES/64, 256, 0, stream>>>(buck, radial_emb, edge_sh, senders,
                                          wbuf, wpA, wpB, ybf, snd16, flag);
  pass2_reduce<<<N_NODES/2, 256, 0, stream>>>(offs, sv16, wpA, wpB, ybf, snd16,
                                              accb);
  pass2_epilogue<<<N_NODES/16, 256, 0, stream>>>(accb, wbuf, node_scalars,
                                                 node_vectors, species,
                                                 d_out, flag);
}